// Round 10
// baseline (1994.894 us; speedup 1.0000x reference)
//
#include <hip/hip_runtime.h>
#include <stdint.h>

#define B_ 128
#define T_ 1024
#define BT_ (B_*T_)
#define H_ 64
#define G_ 192
#define PL_ 432
#define NP_ 5
#define FUSED_ 288
#define N_IN 41

typedef unsigned short u16;
typedef __attribute__((ext_vector_type(8))) short bf16x8;
typedef __attribute__((ext_vector_type(4))) float f32x4;
typedef _Float16 h2 __attribute__((ext_vector_type(2)));
typedef _Float16 h8 __attribute__((ext_vector_type(8)));

__device__ inline float bf2f(u16 u){ union{float f; unsigned int i;} c; c.i = ((unsigned int)u)<<16; return c.f; }
__device__ inline u16 f2bf(float f){ unsigned int u = __float_as_uint(f); unsigned int r = (u + 0x7fffu + ((u>>16)&1u))>>16; return (u16)r; }
__device__ inline _Float16 bf2h(u16 u){ return (_Float16)bf2f(u); }
__device__ inline float sigm(float x){ return 1.f/(1.f+__expf(-x)); }
__device__ inline float tanh_(float x){ float t = __expf(fminf(fmaxf(2.f*x,-30.f),30.f)); return (t-1.f)/(t+1.f); }
__device__ inline float gelu_(float x){ return 0.5f*x*(1.f + erff(x*0.70710678118654752f)); }
__device__ inline float wredsum(float v){
  #pragma unroll
  for(int o=32;o>0;o>>=1) v += __shfl_xor(v,o);
  return v;
}

#if __has_builtin(__builtin_amdgcn_fdot2)
__device__ inline float dot2(h2 a, h2 b, float c){ return __builtin_amdgcn_fdot2(a, b, c, false); }
#else
__device__ inline float dot2(h2 a, h2 b, float c){ return c + (float)a.x*(float)b.x + (float)a.y*(float)b.y; }
#endif

// ---------------- input canonicalization: anything -> bf16 in ws ----------------
struct CvtArgs {
  const void* src[N_IN];
  unsigned dstOff[N_IN];
  unsigned cnt[N_IN];
  unsigned blkStart[N_IN+1];
};

__global__ __launch_bounds__(256) void convert_k(CvtArgs a, u16* __restrict__ dst){
  const bool isbf = (((const u16*)a.src[21])[0] == 0x3F80u);
  int b = blockIdx.x;
  int lo = 0, hi = N_IN;
  while (hi - lo > 1){ int mid = (lo+hi)>>1; if (a.blkStart[mid] <= (unsigned)b) lo = mid; else hi = mid; }
  const int i = lo;
  const unsigned lb = (unsigned)b - a.blkStart[i];
  const unsigned n = a.cnt[i];
  u16* d = dst + a.dstOff[i];
  if (isbf){
    const u16* s = (const u16*)a.src[i];
    #pragma unroll
    for(int e=0;e<8;e++){ unsigned idx = lb*2048u + e*256u + threadIdx.x; if (idx < n) d[idx] = s[idx]; }
  } else {
    const float* s = (const float*)a.src[i];
    #pragma unroll
    for(int e=0;e<8;e++){ unsigned idx = lb*2048u + e*256u + threadIdx.x; if (idx < n) d[idx] = f2bf(s[idx]); }
  }
}

// ---------------- gi = A @ [Wf;Wb]^T + [bf;bb]  (bf16 MFMA GEMM) ----------------
template<int K>
__global__ __launch_bounds__(256) void gi_gemm(const u16* __restrict__ A,
    const u16* __restrict__ Wf, const u16* __restrict__ Wb,
    const u16* __restrict__ biasF, const u16* __restrict__ biasB,
    u16* __restrict__ out)
{
  const int wv = threadIdx.x >> 6, lane = threadIdx.x & 63;
  const int l15 = lane & 15, quad = lane >> 4;
  const size_t mBase = (size_t)blockIdx.x*64 + wv*16;

  bf16x8 afr[K/32];
  #pragma unroll
  for(int kc=0;kc<K/32;kc++)
    afr[kc] = *(const bf16x8*)(A + (mBase + l15)*K + kc*32 + quad*8);

  #pragma unroll
  for(int half=0; half<2; ++half){
    const u16* W    = half ? Wb : Wf;
    const u16* bias = half ? biasB : biasF;
    u16* o = out + (size_t)half * BT_ * G_;
    for(int nt=0; nt<12; ++nt){
      int n = nt*16 + l15;
      f32x4 acc = {0.f,0.f,0.f,0.f};
      #pragma unroll
      for(int kc=0;kc<K/32;kc++){
        bf16x8 bfr = *(const bf16x8*)(W + n*K + kc*32 + quad*8);
        acc = __builtin_amdgcn_mfma_f32_16x16x32_bf16(afr[kc], bfr, acc, 0,0,0);
      }
      float bv = bf2f(bias[n]);
      #pragma unroll
      for(int r=0;r<4;r++){
        size_t row = mBase + quad*4 + r;
        o[row*G_ + n] = f2bf(acc[r] + bv);
      }
    }
  }
}

// ---------------- GRU recurrence: TWO chains per wave ----------------
// 128 blocks x 64 threads = 1 wave/CU handling TWO same-direction chains
// (2k, 2k+1). Same-dir chains share Whh -> the 96 weight VGPRs are reused;
// only accumulators/h/gi staging duplicate. The two recurrences are
// independent, so their exposed latencies (LDS h round-trip, v_exp chains,
// dot2 dep chains) overlap — R9 showed a single chain leaves the wave idle
// ~40% (VALUBusy 15.3/25). gi staged global->LDS in 16-step chunks via async
// global_load_lds (12 x 1KB DMA, double-buffered, ONE vmcnt(0) per 16 steps).
// amdgpu_waves_per_eu(1,1) pins the register budget (no weight spill).
// No barriers: single-wave lockstep + in-order DS.
__global__ __launch_bounds__(64)
__attribute__((amdgpu_waves_per_eu(1,1)))
void recur(const u16* __restrict__ gi,
    const u16* __restrict__ WhF, const u16* __restrict__ WhB,
    const u16* __restrict__ bhF, const u16* __restrict__ bhB,
    u16* __restrict__ y_x1, float* __restrict__ hfin, int layer)
{
  const int blk = blockIdx.x;          // 0..127
  const int dir = blk >> 6;
  const int b0 = (blk & 63) * 2;       // chains b0, b0+1 (same dir)
  const int j = threadIdx.x;           // lane 0..63
  const u16* Wh = dir ? WhB : WhF;
  const u16* bh = dir ? bhB : bhF;

  // this lane's three Whh rows as packed f16 pairs (bf16->f16 is exact)
  h2 wr[32], wz[32], wn[32];
  #pragma unroll
  for(int k8=0;k8<8;k8++){
    uint4 q;
    q = *(const uint4*)(Wh + (size_t)j*64 + k8*8);
    wr[4*k8+0] = (h2){bf2h((u16)(q.x&0xffffu)), bf2h((u16)(q.x>>16))};
    wr[4*k8+1] = (h2){bf2h((u16)(q.y&0xffffu)), bf2h((u16)(q.y>>16))};
    wr[4*k8+2] = (h2){bf2h((u16)(q.z&0xffffu)), bf2h((u16)(q.z>>16))};
    wr[4*k8+3] = (h2){bf2h((u16)(q.w&0xffffu)), bf2h((u16)(q.w>>16))};
    q = *(const uint4*)(Wh + (size_t)(64+j)*64 + k8*8);
    wz[4*k8+0] = (h2){bf2h((u16)(q.x&0xffffu)), bf2h((u16)(q.x>>16))};
    wz[4*k8+1] = (h2){bf2h((u16)(q.y&0xffffu)), bf2h((u16)(q.y>>16))};
    wz[4*k8+2] = (h2){bf2h((u16)(q.z&0xffffu)), bf2h((u16)(q.z>>16))};
    wz[4*k8+3] = (h2){bf2h((u16)(q.w&0xffffu)), bf2h((u16)(q.w>>16))};
    q = *(const uint4*)(Wh + (size_t)(128+j)*64 + k8*8);
    wn[4*k8+0] = (h2){bf2h((u16)(q.x&0xffffu)), bf2h((u16)(q.x>>16))};
    wn[4*k8+1] = (h2){bf2h((u16)(q.y&0xffffu)), bf2h((u16)(q.y>>16))};
    wn[4*k8+2] = (h2){bf2h((u16)(q.z&0xffffu)), bf2h((u16)(q.z>>16))};
    wn[4*k8+3] = (h2){bf2h((u16)(q.w&0xffffu)), bf2h((u16)(q.w>>16))};
  }
  const float bhr = bf2f(bh[j]), bhz = bf2f(bh[64+j]), bhn = bf2f(bh[128+j]);

  __shared__ __align__(16) u16 giLds[2][2][3072];  // [buf][chain][16 x 192]
  __shared__ _Float16 hA[64], hB[64];
  h8* hA8 = (h8*)hA; h8* hB8 = (h8*)hB;
  hA[j] = (_Float16)0.f; hB[j] = (_Float16)0.f;

  const u16* giC0 = gi + (size_t)(dir*128 + b0    ) * T_ * G_;
  const u16* giC1 = gi + (size_t)(dir*128 + b0 + 1) * T_ * G_;

  // async chunk DMA: 16 rows (6144 B) per chain as 6 x (64 lanes x 16 B)
  auto issue_chunk = [&](int c, int buf){
    int tbase = dir ? (1008 - c*16) : (c*16);
    const u16* s0 = giC0 + (size_t)tbase*G_ + j*8;
    const u16* s1 = giC1 + (size_t)tbase*G_ + j*8;
    u16* d0 = &giLds[buf][0][0];
    u16* d1 = &giLds[buf][1][0];
    #pragma unroll
    for(int i=0;i<6;i++){
      __builtin_amdgcn_global_load_lds(
        (const __attribute__((address_space(1))) void*)(s0 + i*512),
        (__attribute__((address_space(3))) void*)(d0 + i*512), 16, 0, 0);
      __builtin_amdgcn_global_load_lds(
        (const __attribute__((address_space(1))) void*)(s1 + i*512),
        (__attribute__((address_space(3))) void*)(d1 + i*512), 16, 0, 0);
    }
  };

  issue_chunk(0, 0);

  float ha = 0.f, hb_ = 0.f;
  for(int c=0; c<64; ++c){
    asm volatile("s_waitcnt vmcnt(0)" ::: "memory");  // chunk c landed in LDS
    if (c < 63) issue_chunk(c+1, (c+1)&1);
    const u16* g0 = &giLds[c&1][0][0];
    const u16* g1 = &giLds[c&1][1][0];
    for(int ls=0; ls<16; ++ls){
      int row = dir ? (15-ls) : ls;
      const u16* r0p = g0 + row*G_;
      const u16* r1p = g1 + row*G_;
      // two independent matvecs, interleaved (shared weights)
      float ar0=bhr, ar1=0.f, az0=bhz, az1=0.f, an0=bhn, an1=0.f;
      float br0=bhr, br1=0.f, bz0=bhz, bz1=0.f, bn0=bhn, bn1=0.f;
      #pragma unroll
      for(int k=0;k<8;k++){
        h8 va = hA8[k], vb = hB8[k];
        h2 a0 = __builtin_shufflevector(va, va, 0, 1);
        h2 a1 = __builtin_shufflevector(va, va, 2, 3);
        h2 a2 = __builtin_shufflevector(va, va, 4, 5);
        h2 a3 = __builtin_shufflevector(va, va, 6, 7);
        h2 b0v = __builtin_shufflevector(vb, vb, 0, 1);
        h2 b1v = __builtin_shufflevector(vb, vb, 2, 3);
        h2 b2v = __builtin_shufflevector(vb, vb, 4, 5);
        h2 b3v = __builtin_shufflevector(vb, vb, 6, 7);
        ar0 = dot2(wr[4*k+0], a0, ar0); br0 = dot2(wr[4*k+0], b0v, br0);
        ar1 = dot2(wr[4*k+1], a1, ar1); br1 = dot2(wr[4*k+1], b1v, br1);
        ar0 = dot2(wr[4*k+2], a2, ar0); br0 = dot2(wr[4*k+2], b2v, br0);
        ar1 = dot2(wr[4*k+3], a3, ar1); br1 = dot2(wr[4*k+3], b3v, br1);
        az0 = dot2(wz[4*k+0], a0, az0); bz0 = dot2(wz[4*k+0], b0v, bz0);
        az1 = dot2(wz[4*k+1], a1, az1); bz1 = dot2(wz[4*k+1], b1v, bz1);
        az0 = dot2(wz[4*k+2], a2, az0); bz0 = dot2(wz[4*k+2], b2v, bz0);
        az1 = dot2(wz[4*k+3], a3, az1); bz1 = dot2(wz[4*k+3], b3v, bz1);
        an0 = dot2(wn[4*k+0], a0, an0); bn0 = dot2(wn[4*k+0], b0v, bn0);
        an1 = dot2(wn[4*k+1], a1, an1); bn1 = dot2(wn[4*k+1], b1v, bn1);
        an0 = dot2(wn[4*k+2], a2, an0); bn0 = dot2(wn[4*k+2], b2v, bn0);
        an1 = dot2(wn[4*k+3], a3, an1); bn1 = dot2(wn[4*k+3], b3v, bn1);
      }
      float agr = bf2f(r0p[j]), agz = bf2f(r0p[64+j]), agn = bf2f(r0p[128+j]);
      float bgr = bf2f(r1p[j]), bgz = bf2f(r1p[64+j]), bgn = bf2f(r1p[128+j]);

      float arr = sigm(agr + (ar0+ar1));
      float brr = sigm(bgr + (br0+br1));
      float azz = sigm(agz + (az0+az1));
      float bzz = sigm(bgz + (bz0+bz1));
      float ann = tanh_(agn + arr*(an0+an1));
      float bnn = tanh_(bgn + brr*(bn0+bn1));
      ha  = (1.f - azz)*ann + azz*ha;
      hb_ = (1.f - bzz)*bnn + bzz*hb_;

      hA[j] = (_Float16)ha;            // in-order DS; next iter's reads see it
      hB[j] = (_Float16)hb_;

      if (layer == 0){
        int s = c*16 + ls;
        int t = dir ? (T_-1-s) : s;
        y_x1[((size_t)b0*T_ + t)*128 + dir*64 + j] = f2bf(ha);
        y_x1[((size_t)(b0+1)*T_ + t)*128 + dir*64 + j] = f2bf(hb_);
      }
    }
  }
  if (layer == 1){
    hfin[b0*FUSED_ + dir*64 + j] = ha;
    hfin[(b0+1)*FUSED_ + dir*64 + j] = hb_;
  }
}

// ---------------- static branch: embed + LN + gates ----------------
__global__ __launch_bounds__(64) void static_k(const u16* __restrict__ sx,
   const u16* __restrict__ smW, const u16* __restrict__ smb,
   const u16* __restrict__ lng, const u16* __restrict__ lnb,
   const u16* __restrict__ gW, const u16* __restrict__ gb,
   float* __restrict__ fused, float* __restrict__ gates)
{
  int b = blockIdx.x, j = threadIdx.x;
  float xr[16];
  #pragma unroll
  for(int k=0;k<16;k++) xr[k] = bf2f(sx[b*16+k]);
  float acc = bf2f(smb[j]);
  #pragma unroll
  for(int k=0;k<16;k++) acc += xr[k]*bf2f(smW[j*16+k]);
  float xg = gelu_(acc);
  float m = wredsum(xg)*(1.f/64.f);
  float d = xg - m;
  float v = wredsum(d*d)*(1.f/64.f);
  float se = d*rsqrtf(v+1e-5f)*bf2f(lng[j]) + bf2f(lnb[j]);
  fused[b*FUSED_ + 128 + j] = se;
  #pragma unroll
  for(int i=0;i<5;i++){
    float p = se*bf2f(gW[i*64+j]);
    float s = wredsum(p);
    if (j == 0) gates[b*5+i] = sigm(s + bf2f(gb[i]));
  }
}

// ---------------- qkv = (phys*gates)^T @ attn_in_W^T + b ----------------
__global__ __launch_bounds__(448) void qkv_k(const u16* __restrict__ phys,
   const float* __restrict__ gates, const u16* __restrict__ aW,
   const u16* __restrict__ ab, float* __restrict__ qkv)
{
  int b = blockIdx.x, l = threadIdx.x;
  if (l >= PL_) return;
  float pv[5];
  #pragma unroll
  for(int i=0;i<5;i++) pv[i] = bf2f(phys[((size_t)b*5+i)*PL_ + l]) * gates[b*5+i];
  #pragma unroll
  for(int c=0;c<15;c++){
    float a = bf2f(ab[c]);
    #pragma unroll
    for(int i=0;i<5;i++) a += pv[i]*bf2f(aW[c*5+i]);
    qkv[((size_t)b*15+c)*PL_ + l] = a;
  }
}

// ---------------- attention (rank-1 scores, softmax over j) ----------------
__global__ __launch_bounds__(256) void attn_k(const float* __restrict__ qkv,
                                              float* __restrict__ ao)
{
  int h = blockIdx.x, b = blockIdx.y;
  int tid = threadIdx.x;
  __shared__ float kS[PL_], vS[PL_];
  __shared__ float red[32];
  const float* qb = qkv + ((size_t)b*15 + h)*PL_;
  const float* kb = qkv + ((size_t)b*15 + 5 + h)*PL_;
  const float* vb = qkv + ((size_t)b*15 + 10 + h)*PL_;
  for(int j=tid;j<PL_;j+=256){ kS[j]=kb[j]; vS[j]=vb[j]; }
  __syncthreads();
  float lmax=-1e30f, lmin=1e30f;
  for(int j=tid;j<PL_;j+=256){ float kv=kS[j]; lmax=fmaxf(lmax,kv); lmin=fminf(lmin,kv); }
  #pragma unroll
  for(int o=32;o>0;o>>=1){ lmax=fmaxf(lmax,__shfl_xor(lmax,o)); lmin=fminf(lmin,__shfl_xor(lmin,o)); }
  int wv = tid>>6;
  if ((tid&63)==0){ red[wv]=lmax; red[8+wv]=lmin; }
  __syncthreads();
  if (tid==0){
    float mx=red[0], mn=red[8];
    for(int i=1;i<4;i++){ mx=fmaxf(mx,red[i]); mn=fminf(mn,red[8+i]); }
    red[16]=mx; red[17]=mn;
  }
  __syncthreads();
  float kmx=red[16], kmn=red[17];
  for(int i=tid;i<PL_;i+=256){
    float s = qb[i];
    float m = fmaxf(s*kmx, s*kmn);
    float den=0.f, num=0.f;
    #pragma unroll 4
    for(int j=0;j<PL_;j++){
      float e = __expf(s*kS[j]-m);
      den += e; num += e*vS[j];
    }
    ao[((size_t)b*PL_+i)*5 + h] = num/den;
  }
}

// ---------------- output projection ----------------
__global__ __launch_bounds__(448) void proj_k(const float* __restrict__ ao,
   const u16* __restrict__ oW, const u16* __restrict__ ob, float* __restrict__ p2)
{
  int b = blockIdx.x, l = threadIdx.x;
  if (l >= PL_) return;
  float a[5];
  #pragma unroll
  for(int hh=0;hh<5;hh++) a[hh] = ao[((size_t)b*PL_+l)*5 + hh];
  #pragma unroll
  for(int c=0;c<5;c++){
    float s = bf2f(ob[c]);
    #pragma unroll
    for(int hh=0;hh<5;hh++) s += a[hh]*bf2f(oW[c*5+hh]);
    p2[((size_t)b*5+c)*PL_ + l] = s;
  }
}

// ---------------- dilated convs + gelu + mean ----------------
template<int KS, int DIL, int PAD>
__device__ inline void do_conv(const float* pS, const u16* Wc, const u16* bc,
                               float* fused, int b, int o, int p, int cslot)
{
  const int Lout = PL_ + 2*PAD - DIL*(KS-1);
  float w[5][KS];
  #pragma unroll
  for(int i=0;i<5;i++)
    #pragma unroll
    for(int t=0;t<KS;t++) w[i][t] = bf2f(Wc[(o*5+i)*KS + t]);
  float bias = bf2f(bc[o]);
  float acc = 0.f;
  for(int l=p; l<Lout; l+=8){
    float s = bias;
    #pragma unroll
    for(int t=0;t<KS;t++){
      int idx = l - PAD + t*DIL;
      if (idx >= 0 && idx < PL_){
        #pragma unroll
        for(int i=0;i<5;i++) s += w[i][t]*pS[i*PL_ + idx];
      }
    }
    acc += gelu_(s);
  }
  #pragma unroll
  for(int off=1;off<8;off<<=1) acc += __shfl_xor(acc,off);
  if (p == 0) fused[b*FUSED_ + 192 + cslot*32 + o] = acc/(float)Lout;
}

__global__ __launch_bounds__(256) void conv_k(const float* __restrict__ p2,
  const u16* __restrict__ W1c, const u16* __restrict__ b1c,
  const u16* __restrict__ W2c, const u16* __restrict__ b2c,
  const u16* __restrict__ W3c, const u16* __restrict__ b3c,
  float* __restrict__ fused)
{
  int b = blockIdx.x;
  __shared__ float pS[5*PL_];
  for(int idx=threadIdx.x; idx<5*PL_; idx+=256) pS[idx] = p2[(size_t)b*5*PL_ + idx];
  __syncthreads();
  int o = threadIdx.x >> 3, p = threadIdx.x & 7;
  do_conv<3,1,1>(pS, W1c, b1c, fused, b, o, p, 0);
  do_conv<5,2,2>(pS, W2c, b2c, fused, b, o, p, 1);
  do_conv<9,4,4>(pS, W3c, b3c, fused, b, o, p, 2);
}

// ---------------- head: LN + MLP (output dtype adaptive) ----------------
__global__ __launch_bounds__(448) void head_k(const float* __restrict__ fused,
   const u16* __restrict__ lng, const u16* __restrict__ lnb,
   const u16* __restrict__ W1, const u16* __restrict__ b1,
   const u16* __restrict__ W2, const u16* __restrict__ b2,
   void* __restrict__ out, const u16* __restrict__ detect)
{
  const bool isbf = (detect[0] == 0x3F80u);
  int b = blockIdx.x, tid = threadIdx.x;
  __shared__ float fS[FUSED_];
  __shared__ float hS[128];
  __shared__ float red[32];
  float v = (tid < FUSED_) ? fused[b*FUSED_ + tid] : 0.f;
  float s1 = wredsum(v);
  float s2 = wredsum(v*v);
  int wv = tid>>6;
  if ((tid&63)==0){ red[wv]=s1; red[8+wv]=s2; }
  __syncthreads();
  if (tid==0){
    float S=0.f, SS=0.f;
    for(int i=0;i<7;i++){ S+=red[i]; SS+=red[8+i]; }
    float m = S/288.f;
    red[16]=m; red[17]=SS/288.f - m*m;
  }
  __syncthreads();
  float m = red[16], var = red[17];
  if (tid < FUSED_) fS[tid] = (v-m)*rsqrtf(var+1e-5f)*bf2f(lng[tid]) + bf2f(lnb[tid]);
  __syncthreads();
  if (tid < 128){
    float a = bf2f(b1[tid]);
    const u16* wr = W1 + (size_t)tid*FUSED_;
    #pragma unroll
    for(int k8=0;k8<36;k8++){
      uint4 q = *(const uint4*)(wr + k8*8);
      a += fS[8*k8+0]*bf2f((u16)(q.x&0xffffu)) + fS[8*k8+1]*bf2f((u16)(q.x>>16))
         + fS[8*k8+2]*bf2f((u16)(q.y&0xffffu)) + fS[8*k8+3]*bf2f((u16)(q.y>>16))
         + fS[8*k8+4]*bf2f((u16)(q.z&0xffffu)) + fS[8*k8+5]*bf2f((u16)(q.z>>16))
         + fS[8*k8+6]*bf2f((u16)(q.w&0xffffu)) + fS[8*k8+7]*bf2f((u16)(q.w>>16));
    }
    hS[tid] = gelu_(a);
  }
  __syncthreads();
  if (tid < PL_){
    float a = bf2f(b2[tid]);
    const u16* wr = W2 + (size_t)tid*128;
    #pragma unroll
    for(int k8=0;k8<16;k8++){
      uint4 q = *(const uint4*)(wr + k8*8);
      a += hS[8*k8+0]*bf2f((u16)(q.x&0xffffu)) + hS[8*k8+1]*bf2f((u16)(q.x>>16))
         + hS[8*k8+2]*bf2f((u16)(q.y&0xffffu)) + hS[8*k8+3]*bf2f((u16)(q.y>>16))
         + hS[8*k8+4]*bf2f((u16)(q.z&0xffffu)) + hS[8*k8+5]*bf2f((u16)(q.z>>16))
         + hS[8*k8+6]*bf2f((u16)(q.w&0xffffu)) + hS[8*k8+7]*bf2f((u16)(q.w>>16));
    }
    size_t oi = (size_t)b*PL_ + tid;
    if (isbf) ((u16*)out)[oi] = f2bf(a);
    else      ((float*)out)[oi] = a;
  }
}

extern "C" void kernel_launch(void* const* d_in, const int* in_sizes, int n_in,
                              void* d_out, int out_size, void* d_ws, size_t ws_size,
                              hipStream_t stream)
{
  static const unsigned cnts[N_IN] = {
    4194304, 2048, 276480,
    6144, 12288, 192, 192,
    6144, 12288, 192, 192,
    24576, 12288, 192, 192,
    24576, 12288, 192, 192,
    1024, 64, 64, 64,
    320, 5,
    75, 15,
    25, 5,
    480, 32, 800, 32, 1440, 32,
    288, 288,
    36864, 128, 55296, 432
  };

  char* ws = (char*)d_ws;
  size_t off = 0;
  auto alloc = [&](size_t bytes){ size_t o = off; off = (off + bytes + 255) & ~(size_t)255; return o; };

  CvtArgs ca;
  const u16* cin[N_IN];
  unsigned totalBlocks = 0;
  for (int i=0;i<N_IN;i++){
    ca.src[i] = d_in[i];
    ca.cnt[i] = cnts[i];
    size_t o = alloc((size_t)cnts[i]*2);
    ca.dstOff[i] = (unsigned)(o/2);
    cin[i] = (const u16*)(ws + o);
    ca.blkStart[i] = totalBlocks;
    totalBlocks += (cnts[i] + 2047u)/2048u;
  }
  ca.blkStart[N_IN] = totalBlocks;
  u16* canon = (u16*)ws;

  u16*   gi    = (u16*)  (ws + alloc((size_t)2*BT_*G_*2));
  u16*   x1    = (u16*)  (ws + alloc((size_t)BT_*128*2));
  float* fused = (float*)(ws + alloc((size_t)B_*FUSED_*4));
  float* gates = (float*)(ws + alloc((size_t)B_*5*4));
  float* qkv   = (float*)(ws + alloc((size_t)B_*15*PL_*4));
  float* ao    = (float*)(ws + alloc((size_t)B_*PL_*5*4));
  float* p2    = (float*)(ws + alloc((size_t)B_*5*PL_*4));
  (void)ws_size; (void)in_sizes; (void)n_in; (void)out_size;

  convert_k<<<totalBlocks, 256, 0, stream>>>(ca, canon);

  gi_gemm<32><<<BT_/64, 256, 0, stream>>>(cin[0], cin[3], cin[7], cin[5], cin[9], gi);
  recur<<<128, 64, 0, stream>>>(gi, cin[4], cin[8], cin[6], cin[10], x1, nullptr, 0);
  gi_gemm<128><<<BT_/64, 256, 0, stream>>>(x1, cin[11], cin[15], cin[13], cin[17], gi);
  recur<<<128, 64, 0, stream>>>(gi, cin[12], cin[16], cin[14], cin[18], nullptr, fused, 1);
  static_k<<<128, 64, 0, stream>>>(cin[1], cin[19], cin[20], cin[21], cin[22], cin[23], cin[24], fused, gates);
  qkv_k<<<128, 448, 0, stream>>>(cin[2], gates, cin[25], cin[26], qkv);
  attn_k<<<dim3(5,128), 256, 0, stream>>>(qkv, ao);
  proj_k<<<128, 448, 0, stream>>>(ao, cin[27], cin[28], p2);
  conv_k<<<128, 256, 0, stream>>>(p2, cin[29], cin[30], cin[31], cin[32], cin[33], cin[34], fused);
  head_k<<<128, 448, 0, stream>>>(fused, cin[35], cin[36], cin[37], cin[38], cin[39], cin[40],
                                  d_out, (const u16*)d_in[21]);
}

// Round 11
// 1481.809 us; speedup vs baseline: 1.3463x; 1.3463x over previous
//
#include <hip/hip_runtime.h>
#include <stdint.h>

#define B_ 128
#define T_ 1024
#define BT_ (B_*T_)
#define H_ 64
#define G_ 192
#define PL_ 432
#define NP_ 5
#define FUSED_ 288
#define N_IN 41

typedef unsigned short u16;
typedef __attribute__((ext_vector_type(8))) short bf16x8;
typedef __attribute__((ext_vector_type(4))) float f32x4;
typedef _Float16 h2 __attribute__((ext_vector_type(2)));
typedef _Float16 h8 __attribute__((ext_vector_type(8)));

__device__ inline float bf2f(u16 u){ union{float f; unsigned int i;} c; c.i = ((unsigned int)u)<<16; return c.f; }
__device__ inline u16 f2bf(float f){ unsigned int u = __float_as_uint(f); unsigned int r = (u + 0x7fffu + ((u>>16)&1u))>>16; return (u16)r; }
__device__ inline _Float16 bf2h(u16 u){ return (_Float16)bf2f(u); }
__device__ inline float sigm(float x){ return 1.f/(1.f+__expf(-x)); }
__device__ inline float tanh_(float x){ float t = __expf(fminf(fmaxf(2.f*x,-30.f),30.f)); return (t-1.f)/(t+1.f); }
__device__ inline float gelu_(float x){ return 0.5f*x*(1.f + erff(x*0.70710678118654752f)); }
__device__ inline float wredsum(float v){
  #pragma unroll
  for(int o=32;o>0;o>>=1) v += __shfl_xor(v,o);
  return v;
}
// Workgroup barrier that does NOT drain vmcnt (keeps wave3's DMA in flight).
__device__ inline void wg_barrier(){
  asm volatile("s_waitcnt lgkmcnt(0)\n\ts_barrier" ::: "memory");
}

#if __has_builtin(__builtin_amdgcn_fdot2)
__device__ inline float dot2(h2 a, h2 b, float c){ return __builtin_amdgcn_fdot2(a, b, c, false); }
#else
__device__ inline float dot2(h2 a, h2 b, float c){ return c + (float)a.x*(float)b.x + (float)a.y*(float)b.y; }
#endif

// ---------------- input canonicalization: anything -> bf16 in ws ----------------
struct CvtArgs {
  const void* src[N_IN];
  unsigned dstOff[N_IN];
  unsigned cnt[N_IN];
  unsigned blkStart[N_IN+1];
};

__global__ __launch_bounds__(256) void convert_k(CvtArgs a, u16* __restrict__ dst){
  const bool isbf = (((const u16*)a.src[21])[0] == 0x3F80u);
  int b = blockIdx.x;
  int lo = 0, hi = N_IN;
  while (hi - lo > 1){ int mid = (lo+hi)>>1; if (a.blkStart[mid] <= (unsigned)b) lo = mid; else hi = mid; }
  const int i = lo;
  const unsigned lb = (unsigned)b - a.blkStart[i];
  const unsigned n = a.cnt[i];
  u16* d = dst + a.dstOff[i];
  if (isbf){
    const u16* s = (const u16*)a.src[i];
    #pragma unroll
    for(int e=0;e<8;e++){ unsigned idx = lb*2048u + e*256u + threadIdx.x; if (idx < n) d[idx] = s[idx]; }
  } else {
    const float* s = (const float*)a.src[i];
    #pragma unroll
    for(int e=0;e<8;e++){ unsigned idx = lb*2048u + e*256u + threadIdx.x; if (idx < n) d[idx] = f2bf(s[idx]); }
  }
}

// ---------------- gi = A @ [Wf;Wb]^T + [bf;bb]  (bf16 MFMA GEMM) ----------------
template<int K>
__global__ __launch_bounds__(256) void gi_gemm(const u16* __restrict__ A,
    const u16* __restrict__ Wf, const u16* __restrict__ Wb,
    const u16* __restrict__ biasF, const u16* __restrict__ biasB,
    u16* __restrict__ out)
{
  const int wv = threadIdx.x >> 6, lane = threadIdx.x & 63;
  const int l15 = lane & 15, quad = lane >> 4;
  const size_t mBase = (size_t)blockIdx.x*64 + wv*16;

  bf16x8 afr[K/32];
  #pragma unroll
  for(int kc=0;kc<K/32;kc++)
    afr[kc] = *(const bf16x8*)(A + (mBase + l15)*K + kc*32 + quad*8);

  #pragma unroll
  for(int half=0; half<2; ++half){
    const u16* W    = half ? Wb : Wf;
    const u16* bias = half ? biasB : biasF;
    u16* o = out + (size_t)half * BT_ * G_;
    for(int nt=0; nt<12; ++nt){
      int n = nt*16 + l15;
      f32x4 acc = {0.f,0.f,0.f,0.f};
      #pragma unroll
      for(int kc=0;kc<K/32;kc++){
        bf16x8 bfr = *(const bf16x8*)(W + n*K + kc*32 + quad*8);
        acc = __builtin_amdgcn_mfma_f32_16x16x32_bf16(afr[kc], bfr, acc, 0,0,0);
      }
      float bv = bf2f(bias[n]);
      #pragma unroll
      for(int r=0;r<4;r++){
        size_t row = mBase + quad*4 + r;
        o[row*G_ + n] = f2bf(acc[r] + bv);
      }
    }
  }
}

// ---------------- GRU recurrence: 1 chain per block, 4 waves per block ----------------
// 256 blocks x 256 threads. Waves 0-2 (tid<192): thread owns gate-row `tid` of
// Whh (32 VGPRs of f16 weights each, no spill) -> 32 dot2/step, one gate per
// wave, running on 3 of the CU's 4 SIMDs in parallel (R9/R10 showed 1 wave
// uses 1 SIMD and is issue/structure-bound).
// ONE wg_barrier per step: after it, ALL THREE compute waves redundantly
// compute the full activation (identical values -> same-value hS race is
// benign, and each wave's next matvec reads its own in-order DS writes).
// Wave 3 (tid>=192): async global_load_lds chunk staging of gi (16-step
// chunks, double-buffered, vmcnt waits confined to wave 3 so compute waves
// never drain the DMA queue) + bulk y_x1 history writeback off critical path.
__global__ __launch_bounds__(256)
void recur(const u16* __restrict__ gi,
    const u16* __restrict__ WhF, const u16* __restrict__ WhB,
    const u16* __restrict__ bhF, const u16* __restrict__ bhB,
    u16* __restrict__ y_x1, float* __restrict__ hfin, int layer)
{
  const int chain = blockIdx.x;
  const int dir = chain >> 7;
  const int b = chain & 127;
  const int tid = threadIdx.x;
  const int j = tid & 63;
  const u16* Wh = dir ? WhB : WhF;
  const u16* bh = dir ? bhB : bhF;

  __shared__ __align__(16) u16 giL[2][16*G_];     // 2 x 6 KB chunk buffers
  __shared__ float preS[2][192];
  __shared__ __align__(16) _Float16 hS[64];
  __shared__ u16 hHist[2][16][64];
  h8* hS8 = (h8*)hS;

  // compute waves: load this thread's Whh row as packed f16 pairs
  h2 w[32];
  float bias = 0.f;
  if (tid < 192){
    #pragma unroll
    for(int k8=0;k8<8;k8++){
      uint4 q = *(const uint4*)(Wh + (size_t)tid*64 + k8*8);
      w[4*k8+0] = (h2){bf2h((u16)(q.x&0xffffu)), bf2h((u16)(q.x>>16))};
      w[4*k8+1] = (h2){bf2h((u16)(q.y&0xffffu)), bf2h((u16)(q.y>>16))};
      w[4*k8+2] = (h2){bf2h((u16)(q.z&0xffffu)), bf2h((u16)(q.z>>16))};
      w[4*k8+3] = (h2){bf2h((u16)(q.w&0xffffu)), bf2h((u16)(q.w>>16))};
    }
    bias = bf2f(bh[tid]);
  }

  const u16* giC = gi + (size_t)chain * T_ * G_;

  // wave3: async chunk DMA (16 rows = 6144 B = 6 x 64 lanes x 16 B)
  auto issue_chunk = [&](int c, int buf){
    int tbase = dir ? (1008 - c*16) : (c*16);
    const u16* src = giC + (size_t)tbase*G_ + j*8;
    u16* dst = &giL[buf][0];
    #pragma unroll
    for(int i=0;i<6;i++){
      __builtin_amdgcn_global_load_lds(
        (const __attribute__((address_space(1))) void*)(src + i*512),
        (__attribute__((address_space(3))) void*)(dst + i*512), 16, 0, 0);
    }
  };

  if (tid < 64) hS[tid] = (_Float16)0.f;
  if (tid >= 192){
    issue_chunk(0, 0);
    asm volatile("s_waitcnt vmcnt(0)" ::: "memory");
  }
  wg_barrier();

  float h = 0.f;
  for(int s=0; s<T_; ++s){
    const int c = s >> 4, ls = s & 15, p = s & 1;
    const int rls = dir ? (15 - ls) : ls;
    const u16* gbuf = &giL[c & 1][0];

    if (tid < 192){
      // matvec for gate-row tid: 32 dot2, 4 accumulators
      float a0 = 0.f, a1 = 0.f, a2 = 0.f, a3 = 0.f;
      #pragma unroll
      for(int k=0;k<8;k++){
        h8 hv = hS8[k];                // broadcast read (all lanes same addr)
        h2 p0 = __builtin_shufflevector(hv, hv, 0, 1);
        h2 p1 = __builtin_shufflevector(hv, hv, 2, 3);
        h2 p2 = __builtin_shufflevector(hv, hv, 4, 5);
        h2 p3 = __builtin_shufflevector(hv, hv, 6, 7);
        a0 = dot2(w[4*k+0], p0, a0);
        a1 = dot2(w[4*k+1], p1, a1);
        a2 = dot2(w[4*k+2], p2, a2);
        a3 = dot2(w[4*k+3], p3, a3);
      }
      float acc = bias + (a0+a1)+(a2+a3);
      if (tid < 128) acc += bf2f(gbuf[rls*G_ + tid]);   // fold gi for r,z gates
      preS[p][tid] = acc;
    } else {
      if (ls == 15) asm volatile("s_waitcnt vmcnt(0)" ::: "memory"); // next chunk landed
    }

    wg_barrier();

    if (tid < 192){
      // all three compute waves redundantly update h (identical values)
      float pr = preS[p][j];
      float pz = preS[p][64+j];
      float pn = preS[p][128+j];
      float gn = bf2f(gbuf[rls*G_ + 128 + j]);
      float r  = sigm(pr);
      float z  = sigm(pz);
      float nn = tanh_(gn + r*pn);
      h = (1.f - z)*nn + z*h;
      hS[j] = (_Float16)h;             // in-order DS per wave; same value x3
      if (tid < 64) hHist[c&1][ls][j] = f2bf(h);
    } else {
      if (ls == 0){
        int cn = c + 1;
        if (cn < 64) issue_chunk(cn, cn & 1);
        if (layer == 0 && c > 0){
          // write chunk c-1's history (complete as of the barrier just passed)
          int cc = c - 1;
          #pragma unroll 4
          for(int l2=0;l2<16;l2++){
            int s2 = cc*16 + l2;
            int t = dir ? (T_-1-s2) : s2;
            y_x1[((size_t)b*T_ + t)*128 + dir*64 + j] = hHist[cc&1][l2][j];
          }
        }
      }
    }
  }

  wg_barrier();
  if (tid >= 192 && layer == 0){
    // final chunk (63) history
    #pragma unroll 4
    for(int l2=0;l2<16;l2++){
      int s2 = 63*16 + l2;
      int t = dir ? (T_-1-s2) : s2;
      y_x1[((size_t)b*T_ + t)*128 + dir*64 + j] = hHist[1][l2][j];
    }
  }
  if (layer == 1 && tid < 64) hfin[b*FUSED_ + dir*64 + tid] = h;
}

// ---------------- static branch: embed + LN + gates ----------------
__global__ __launch_bounds__(64) void static_k(const u16* __restrict__ sx,
   const u16* __restrict__ smW, const u16* __restrict__ smb,
   const u16* __restrict__ lng, const u16* __restrict__ lnb,
   const u16* __restrict__ gW, const u16* __restrict__ gb,
   float* __restrict__ fused, float* __restrict__ gates)
{
  int b = blockIdx.x, j = threadIdx.x;
  float xr[16];
  #pragma unroll
  for(int k=0;k<16;k++) xr[k] = bf2f(sx[b*16+k]);
  float acc = bf2f(smb[j]);
  #pragma unroll
  for(int k=0;k<16;k++) acc += xr[k]*bf2f(smW[j*16+k]);
  float xg = gelu_(acc);
  float m = wredsum(xg)*(1.f/64.f);
  float d = xg - m;
  float v = wredsum(d*d)*(1.f/64.f);
  float se = d*rsqrtf(v+1e-5f)*bf2f(lng[j]) + bf2f(lnb[j]);
  fused[b*FUSED_ + 128 + j] = se;
  #pragma unroll
  for(int i=0;i<5;i++){
    float p = se*bf2f(gW[i*64+j]);
    float s = wredsum(p);
    if (j == 0) gates[b*5+i] = sigm(s + bf2f(gb[i]));
  }
}

// ---------------- qkv = (phys*gates)^T @ attn_in_W^T + b ----------------
__global__ __launch_bounds__(448) void qkv_k(const u16* __restrict__ phys,
   const float* __restrict__ gates, const u16* __restrict__ aW,
   const u16* __restrict__ ab, float* __restrict__ qkv)
{
  int b = blockIdx.x, l = threadIdx.x;
  if (l >= PL_) return;
  float pv[5];
  #pragma unroll
  for(int i=0;i<5;i++) pv[i] = bf2f(phys[((size_t)b*5+i)*PL_ + l]) * gates[b*5+i];
  #pragma unroll
  for(int c=0;c<15;c++){
    float a = bf2f(ab[c]);
    #pragma unroll
    for(int i=0;i<5;i++) a += pv[i]*bf2f(aW[c*5+i]);
    qkv[((size_t)b*15+c)*PL_ + l] = a;
  }
}

// ---------------- attention (rank-1 scores, softmax over j) ----------------
__global__ __launch_bounds__(256) void attn_k(const float* __restrict__ qkv,
                                              float* __restrict__ ao)
{
  int h = blockIdx.x, b = blockIdx.y;
  int tid = threadIdx.x;
  __shared__ float kS[PL_], vS[PL_];
  __shared__ float red[32];
  const float* qb = qkv + ((size_t)b*15 + h)*PL_;
  const float* kb = qkv + ((size_t)b*15 + 5 + h)*PL_;
  const float* vb = qkv + ((size_t)b*15 + 10 + h)*PL_;
  for(int j=tid;j<PL_;j+=256){ kS[j]=kb[j]; vS[j]=vb[j]; }
  __syncthreads();
  float lmax=-1e30f, lmin=1e30f;
  for(int j=tid;j<PL_;j+=256){ float kv=kS[j]; lmax=fmaxf(lmax,kv); lmin=fminf(lmin,kv); }
  #pragma unroll
  for(int o=32;o>0;o>>=1){ lmax=fmaxf(lmax,__shfl_xor(lmax,o)); lmin=fminf(lmin,__shfl_xor(lmin,o)); }
  int wv = tid>>6;
  if ((tid&63)==0){ red[wv]=lmax; red[8+wv]=lmin; }
  __syncthreads();
  if (tid==0){
    float mx=red[0], mn=red[8];
    for(int i=1;i<4;i++){ mx=fmaxf(mx,red[i]); mn=fminf(mn,red[8+i]); }
    red[16]=mx; red[17]=mn;
  }
  __syncthreads();
  float kmx=red[16], kmn=red[17];
  for(int i=tid;i<PL_;i+=256){
    float s = qb[i];
    float m = fmaxf(s*kmx, s*kmn);
    float den=0.f, num=0.f;
    #pragma unroll 4
    for(int j=0;j<PL_;j++){
      float e = __expf(s*kS[j]-m);
      den += e; num += e*vS[j];
    }
    ao[((size_t)b*PL_+i)*5 + h] = num/den;
  }
}

// ---------------- output projection ----------------
__global__ __launch_bounds__(448) void proj_k(const float* __restrict__ ao,
   const u16* __restrict__ oW, const u16* __restrict__ ob, float* __restrict__ p2)
{
  int b = blockIdx.x, l = threadIdx.x;
  if (l >= PL_) return;
  float a[5];
  #pragma unroll
  for(int hh=0;hh<5;hh++) a[hh] = ao[((size_t)b*PL_+l)*5 + hh];
  #pragma unroll
  for(int c=0;c<5;c++){
    float s = bf2f(ob[c]);
    #pragma unroll
    for(int hh=0;hh<5;hh++) s += a[hh]*bf2f(oW[c*5+hh]);
    p2[((size_t)b*5+c)*PL_ + l] = s;
  }
}

// ---------------- dilated convs + gelu + mean ----------------
template<int KS, int DIL, int PAD>
__device__ inline void do_conv(const float* pS, const u16* Wc, const u16* bc,
                               float* fused, int b, int o, int p, int cslot)
{
  const int Lout = PL_ + 2*PAD - DIL*(KS-1);
  float w[5][KS];
  #pragma unroll
  for(int i=0;i<5;i++)
    #pragma unroll
    for(int t=0;t<KS;t++) w[i][t] = bf2f(Wc[(o*5+i)*KS + t]);
  float bias = bf2f(bc[o]);
  float acc = 0.f;
  for(int l=p; l<Lout; l+=8){
    float s = bias;
    #pragma unroll
    for(int t=0;t<KS;t++){
      int idx = l - PAD + t*DIL;
      if (idx >= 0 && idx < PL_){
        #pragma unroll
        for(int i=0;i<5;i++) s += w[i][t]*pS[i*PL_ + idx];
      }
    }
    acc += gelu_(s);
  }
  #pragma unroll
  for(int off=1;off<8;off<<=1) acc += __shfl_xor(acc,off);
  if (p == 0) fused[b*FUSED_ + 192 + cslot*32 + o] = acc/(float)Lout;
}

__global__ __launch_bounds__(256) void conv_k(const float* __restrict__ p2,
  const u16* __restrict__ W1c, const u16* __restrict__ b1c,
  const u16* __restrict__ W2c, const u16* __restrict__ b2c,
  const u16* __restrict__ W3c, const u16* __restrict__ b3c,
  float* __restrict__ fused)
{
  int b = blockIdx.x;
  __shared__ float pS[5*PL_];
  for(int idx=threadIdx.x; idx<5*PL_; idx+=256) pS[idx] = p2[(size_t)b*5*PL_ + idx];
  __syncthreads();
  int o = threadIdx.x >> 3, p = threadIdx.x & 7;
  do_conv<3,1,1>(pS, W1c, b1c, fused, b, o, p, 0);
  do_conv<5,2,2>(pS, W2c, b2c, fused, b, o, p, 1);
  do_conv<9,4,4>(pS, W3c, b3c, fused, b, o, p, 2);
}

// ---------------- head: LN + MLP (output dtype adaptive) ----------------
__global__ __launch_bounds__(448) void head_k(const float* __restrict__ fused,
   const u16* __restrict__ lng, const u16* __restrict__ lnb,
   const u16* __restrict__ W1, const u16* __restrict__ b1,
   const u16* __restrict__ W2, const u16* __restrict__ b2,
   void* __restrict__ out, const u16* __restrict__ detect)
{
  const bool isbf = (detect[0] == 0x3F80u);
  int b = blockIdx.x, tid = threadIdx.x;
  __shared__ float fS[FUSED_];
  __shared__ float hS[128];
  __shared__ float red[32];
  float v = (tid < FUSED_) ? fused[b*FUSED_ + tid] : 0.f;
  float s1 = wredsum(v);
  float s2 = wredsum(v*v);
  int wv = tid>>6;
  if ((tid&63)==0){ red[wv]=s1; red[8+wv]=s2; }
  __syncthreads();
  if (tid==0){
    float S=0.f, SS=0.f;
    for(int i=0;i<7;i++){ S+=red[i]; SS+=red[8+i]; }
    float m = S/288.f;
    red[16]=m; red[17]=SS/288.f - m*m;
  }
  __syncthreads();
  float m = red[16], var = red[17];
  if (tid < FUSED_) fS[tid] = (v-m)*rsqrtf(var+1e-5f)*bf2f(lng[tid]) + bf2f(lnb[tid]);
  __syncthreads();
  if (tid < 128){
    float a = bf2f(b1[tid]);
    const u16* wr = W1 + (size_t)tid*FUSED_;
    #pragma unroll
    for(int k8=0;k8<36;k8++){
      uint4 q = *(const uint4*)(wr + k8*8);
      a += fS[8*k8+0]*bf2f((u16)(q.x&0xffffu)) + fS[8*k8+1]*bf2f((u16)(q.x>>16))
         + fS[8*k8+2]*bf2f((u16)(q.y&0xffffu)) + fS[8*k8+3]*bf2f((u16)(q.y>>16))
         + fS[8*k8+4]*bf2f((u16)(q.z&0xffffu)) + fS[8*k8+5]*bf2f((u16)(q.z>>16))
         + fS[8*k8+6]*bf2f((u16)(q.w&0xffffu)) + fS[8*k8+7]*bf2f((u16)(q.w>>16));
    }
    hS[tid] = gelu_(a);
  }
  __syncthreads();
  if (tid < PL_){
    float a = bf2f(b2[tid]);
    const u16* wr = W2 + (size_t)tid*128;
    #pragma unroll
    for(int k8=0;k8<16;k8++){
      uint4 q = *(const uint4*)(wr + k8*8);
      a += hS[8*k8+0]*bf2f((u16)(q.x&0xffffu)) + hS[8*k8+1]*bf2f((u16)(q.x>>16))
         + hS[8*k8+2]*bf2f((u16)(q.y&0xffffu)) + hS[8*k8+3]*bf2f((u16)(q.y>>16))
         + hS[8*k8+4]*bf2f((u16)(q.z&0xffffu)) + hS[8*k8+5]*bf2f((u16)(q.z>>16))
         + hS[8*k8+6]*bf2f((u16)(q.w&0xffffu)) + hS[8*k8+7]*bf2f((u16)(q.w>>16));
    }
    size_t oi = (size_t)b*PL_ + tid;
    if (isbf) ((u16*)out)[oi] = f2bf(a);
    else      ((float*)out)[oi] = a;
  }
}

extern "C" void kernel_launch(void* const* d_in, const int* in_sizes, int n_in,
                              void* d_out, int out_size, void* d_ws, size_t ws_size,
                              hipStream_t stream)
{
  static const unsigned cnts[N_IN] = {
    4194304, 2048, 276480,
    6144, 12288, 192, 192,
    6144, 12288, 192, 192,
    24576, 12288, 192, 192,
    24576, 12288, 192, 192,
    1024, 64, 64, 64,
    320, 5,
    75, 15,
    25, 5,
    480, 32, 800, 32, 1440, 32,
    288, 288,
    36864, 128, 55296, 432
  };

  char* ws = (char*)d_ws;
  size_t off = 0;
  auto alloc = [&](size_t bytes){ size_t o = off; off = (off + bytes + 255) & ~(size_t)255; return o; };

  CvtArgs ca;
  const u16* cin[N_IN];
  unsigned totalBlocks = 0;
  for (int i=0;i<N_IN;i++){
    ca.src[i] = d_in[i];
    ca.cnt[i] = cnts[i];
    size_t o = alloc((size_t)cnts[i]*2);
    ca.dstOff[i] = (unsigned)(o/2);
    cin[i] = (const u16*)(ws + o);
    ca.blkStart[i] = totalBlocks;
    totalBlocks += (cnts[i] + 2047u)/2048u;
  }
  ca.blkStart[N_IN] = totalBlocks;
  u16* canon = (u16*)ws;

  u16*   gi    = (u16*)  (ws + alloc((size_t)2*BT_*G_*2));
  u16*   x1    = (u16*)  (ws + alloc((size_t)BT_*128*2));
  float* fused = (float*)(ws + alloc((size_t)B_*FUSED_*4));
  float* gates = (float*)(ws + alloc((size_t)B_*5*4));
  float* qkv   = (float*)(ws + alloc((size_t)B_*15*PL_*4));
  float* ao    = (float*)(ws + alloc((size_t)B_*PL_*5*4));
  float* p2    = (float*)(ws + alloc((size_t)B_*5*PL_*4));
  (void)ws_size; (void)in_sizes; (void)n_in; (void)out_size;

  convert_k<<<totalBlocks, 256, 0, stream>>>(ca, canon);

  gi_gemm<32><<<BT_/64, 256, 0, stream>>>(cin[0], cin[3], cin[7], cin[5], cin[9], gi);
  recur<<<256, 256, 0, stream>>>(gi, cin[4], cin[8], cin[6], cin[10], x1, nullptr, 0);
  gi_gemm<128><<<BT_/64, 256, 0, stream>>>(x1, cin[11], cin[15], cin[13], cin[17], gi);
  recur<<<256, 256, 0, stream>>>(gi, cin[12], cin[16], cin[14], cin[18], nullptr, fused, 1);
  static_k<<<128, 64, 0, stream>>>(cin[1], cin[19], cin[20], cin[21], cin[22], cin[23], cin[24], fused, gates);
  qkv_k<<<128, 448, 0, stream>>>(cin[2], gates, cin[25], cin[26], qkv);
  attn_k<<<dim3(5,128), 256, 0, stream>>>(qkv, ao);
  proj_k<<<128, 448, 0, stream>>>(ao, cin[27], cin[28], p2);
  conv_k<<<128, 256, 0, stream>>>(p2, cin[29], cin[30], cin[31], cin[32], cin[33], cin[34], fused);
  head_k<<<128, 448, 0, stream>>>(fused, cin[35], cin[36], cin[37], cin[38], cin[39], cin[40],
                                  d_out, (const u16*)d_in[21]);
}

// Round 12
// 1445.520 us; speedup vs baseline: 1.3801x; 1.0251x over previous
//
#include <hip/hip_runtime.h>
#include <stdint.h>

#define B_ 128
#define T_ 1024
#define BT_ (B_*T_)
#define H_ 64
#define G_ 192
#define PL_ 432
#define NP_ 5
#define FUSED_ 288
#define N_IN 41

typedef unsigned short u16;
typedef __attribute__((ext_vector_type(8))) short bf16x8;
typedef __attribute__((ext_vector_type(4))) float f32x4;

__device__ inline float bf2f(u16 u){ union{float f; unsigned int i;} c; c.i = ((unsigned int)u)<<16; return c.f; }
__device__ inline u16 f2bf(float f){ unsigned int u = __float_as_uint(f); unsigned int r = (u + 0x7fffu + ((u>>16)&1u))>>16; return (u16)r; }
__device__ inline float sigm(float x){ return 1.f/(1.f+__expf(-x)); }
__device__ inline float tanh_(float x){ float t = __expf(fminf(fmaxf(2.f*x,-30.f),30.f)); return (t-1.f)/(t+1.f); }
__device__ inline float gelu_(float x){ return 0.5f*x*(1.f + erff(x*0.70710678118654752f)); }
__device__ inline float wredsum(float v){
  #pragma unroll
  for(int o=32;o>0;o>>=1) v += __shfl_xor(v,o);
  return v;
}

// ---------------- input canonicalization: anything -> bf16 in ws ----------------
struct CvtArgs {
  const void* src[N_IN];
  unsigned dstOff[N_IN];
  unsigned cnt[N_IN];
  unsigned blkStart[N_IN+1];
};

__global__ __launch_bounds__(256) void convert_k(CvtArgs a, u16* __restrict__ dst){
  const bool isbf = (((const u16*)a.src[21])[0] == 0x3F80u);
  int b = blockIdx.x;
  int lo = 0, hi = N_IN;
  while (hi - lo > 1){ int mid = (lo+hi)>>1; if (a.blkStart[mid] <= (unsigned)b) lo = mid; else hi = mid; }
  const int i = lo;
  const unsigned lb = (unsigned)b - a.blkStart[i];
  const unsigned n = a.cnt[i];
  u16* d = dst + a.dstOff[i];
  if (isbf){
    const u16* s = (const u16*)a.src[i];
    #pragma unroll
    for(int e=0;e<8;e++){ unsigned idx = lb*2048u + e*256u + threadIdx.x; if (idx < n) d[idx] = s[idx]; }
  } else {
    const float* s = (const float*)a.src[i];
    #pragma unroll
    for(int e=0;e<8;e++){ unsigned idx = lb*2048u + e*256u + threadIdx.x; if (idx < n) d[idx] = f2bf(s[idx]); }
  }
}

// ---------------- gi = A @ [Wf;Wb]^T + [bf;bb]  (bf16 MFMA GEMM) ----------------
template<int K>
__global__ __launch_bounds__(256) void gi_gemm(const u16* __restrict__ A,
    const u16* __restrict__ Wf, const u16* __restrict__ Wb,
    const u16* __restrict__ biasF, const u16* __restrict__ biasB,
    u16* __restrict__ out)
{
  const int wv = threadIdx.x >> 6, lane = threadIdx.x & 63;
  const int l15 = lane & 15, quad = lane >> 4;
  const size_t mBase = (size_t)blockIdx.x*64 + wv*16;

  bf16x8 afr[K/32];
  #pragma unroll
  for(int kc=0;kc<K/32;kc++)
    afr[kc] = *(const bf16x8*)(A + (mBase + l15)*K + kc*32 + quad*8);

  #pragma unroll
  for(int half=0; half<2; ++half){
    const u16* W    = half ? Wb : Wf;
    const u16* bias = half ? biasB : biasF;
    u16* o = out + (size_t)half * BT_ * G_;
    for(int nt=0; nt<12; ++nt){
      int n = nt*16 + l15;
      f32x4 acc = {0.f,0.f,0.f,0.f};
      #pragma unroll
      for(int kc=0;kc<K/32;kc++){
        bf16x8 bfr = *(const bf16x8*)(W + n*K + kc*32 + quad*8);
        acc = __builtin_amdgcn_mfma_f32_16x16x32_bf16(afr[kc], bfr, acc, 0,0,0);
      }
      float bv = bf2f(bias[n]);
      #pragma unroll
      for(int r=0;r<4;r++){
        size_t row = mBase + quad*4 + r;
        o[row*G_ + n] = f2bf(acc[r] + bv);
      }
    }
  }
}

// ---------------- GRU recurrence: ONE WAVE per chain, MFMA matvec ----------------
// 256 blocks x 64 threads = 1 wave/CU, barrier-free (R2/R11: any per-step
// barrier costs >=400cyc; R9/R10: the dot2 VALU matvec is issue-bound at
// ~350 inst/step). The 192x64 matvec moves to the MFMA pipe:
//   pre[n] = Whh[n,:]·h + bhh[n]  as 12 n-tiles x 2 k-chunks of
//   mfma_f32_16x16x32_bf16. A-operand = h replicated over rows (per-lane
//   frag = h[quad*8..+8], 2x ds_read_b128 from LDS). B-operand = Whh row
//   frags, loaded once (96 VGPRs, same pattern as gi_gemm). C-operand =
//   bias frags (AGPR-eligible, unified file). D-layout (m89): lane holds
//   pre[t*16 + (lane&15)] for every tile t; h[lane] needs tiles
//   {q, 4+q, 8+q}, q=lane>>4 -> 9 cndmask selects, no cross-lane ops.
// gi staged global->LDS in 16-step chunks via async global_load_lds
// (R8-proven: one vmcnt(0) per 16 steps). In-order DS makes the h
// write->read correct within the wave.
__global__ __launch_bounds__(64)
__attribute__((amdgpu_waves_per_eu(1,1)))
void recur(const u16* __restrict__ gi,
    const u16* __restrict__ WhF, const u16* __restrict__ WhB,
    const u16* __restrict__ bhF, const u16* __restrict__ bhB,
    u16* __restrict__ y_x1, float* __restrict__ hfin, int layer)
{
  const int chain = blockIdx.x;
  const int dir = chain >> 7;
  const int b = chain & 127;
  const int j = threadIdx.x;           // lane 0..63
  const int l15 = j & 15, quad = j >> 4;
  const u16* Wh = dir ? WhB : WhF;
  const u16* bh = dir ? bhB : bhF;

  // B-fragments: Whh row frags, tile t covers rows t*16..t*16+15
  bf16x8 wf[12][2];
  #pragma unroll
  for(int t=0;t<12;t++){
    #pragma unroll
    for(int c=0;c<2;c++)
      wf[t][c] = *(const bf16x8*)(Wh + (size_t)(t*16 + l15)*64 + c*32 + quad*8);
  }
  // bias C-fragments: all 4 regs = bhh[t*16 + l15]
  f32x4 bfr[12];
  #pragma unroll
  for(int t=0;t<12;t++){
    float bv = bf2f(bh[t*16 + l15]);
    bfr[t] = (f32x4){bv, bv, bv, bv};
  }

  __shared__ __align__(16) u16 giL[2][16*G_];   // 2 x 6KB gi chunk buffers
  __shared__ __align__(16) u16 hB[64];          // h as bf16
  hB[j] = 0;                                    // in-order DS

  const u16* giC = gi + (size_t)chain * T_ * G_;

  auto issue_chunk = [&](int c, int buf){
    int tbase = dir ? (1008 - c*16) : (c*16);
    const u16* src = giC + (size_t)tbase*G_ + j*8;
    u16* dst = &giL[buf][0];
    #pragma unroll
    for(int i=0;i<6;i++){
      __builtin_amdgcn_global_load_lds(
        (const __attribute__((address_space(1))) void*)(src + i*512),
        (__attribute__((address_space(3))) void*)(dst + i*512), 16, 0, 0);
    }
  };

  issue_chunk(0, 0);

  float h = 0.f;
  for(int c=0; c<64; ++c){
    asm volatile("s_waitcnt vmcnt(0)" ::: "memory");  // chunk c landed in LDS
    if (c < 63) issue_chunk(c+1, (c+1)&1);
    const u16* gbuf = &giL[c&1][0];
    #pragma unroll 2
    for(int ls=0; ls<16; ++ls){
      int row = dir ? (15-ls) : ls;
      const u16* rowp = gbuf + row*G_;

      // A-fragments: h[quad*8..+8] (k-chunk 0), h[32+quad*8..+8] (k-chunk 1)
      bf16x8 af0 = *(const bf16x8*)(hB + quad*8);
      bf16x8 af1 = *(const bf16x8*)(hB + 32 + quad*8);

      f32x4 acc[12];
      #pragma unroll
      for(int t=0;t<12;t++){
        acc[t] = __builtin_amdgcn_mfma_f32_16x16x32_bf16(af0, wf[t][0], bfr[t], 0,0,0);
        acc[t] = __builtin_amdgcn_mfma_f32_16x16x32_bf16(af1, wf[t][1], acc[t], 0,0,0);
      }

      // lane j needs pre[q*16+l15] (r), pre[64+..] (z), pre[128+..] (n):
      // tiles q, 4+q, 8+q with q=quad; all 4 acc regs equal, use [0].
      float pr = (quad==0) ? acc[0][0] : (quad==1) ? acc[1][0] : (quad==2) ? acc[2][0] : acc[3][0];
      float pz = (quad==0) ? acc[4][0] : (quad==1) ? acc[5][0] : (quad==2) ? acc[6][0] : acc[7][0];
      float pn = (quad==0) ? acc[8][0] : (quad==1) ? acc[9][0] : (quad==2) ? acc[10][0] : acc[11][0];

      float gr = bf2f(rowp[j]), gz = bf2f(rowp[64+j]), gn = bf2f(rowp[128+j]);

      float r  = sigm(gr + pr);
      float z  = sigm(gz + pz);
      float nn = tanh_(gn + r*pn);
      h = (1.f - z)*nn + z*h;

      hB[j] = f2bf(h);                 // in-order DS; next step's A-frags see it

      if (layer == 0){
        int s = c*16 + ls;
        int t = dir ? (T_-1-s) : s;
        y_x1[((size_t)b*T_ + t)*128 + dir*64 + j] = f2bf(h);
      }
    }
  }
  if (layer == 1) hfin[b*FUSED_ + dir*64 + j] = h;
}

// ---------------- static branch: embed + LN + gates ----------------
__global__ __launch_bounds__(64) void static_k(const u16* __restrict__ sx,
   const u16* __restrict__ smW, const u16* __restrict__ smb,
   const u16* __restrict__ lng, const u16* __restrict__ lnb,
   const u16* __restrict__ gW, const u16* __restrict__ gb,
   float* __restrict__ fused, float* __restrict__ gates)
{
  int b = blockIdx.x, j = threadIdx.x;
  float xr[16];
  #pragma unroll
  for(int k=0;k<16;k++) xr[k] = bf2f(sx[b*16+k]);
  float acc = bf2f(smb[j]);
  #pragma unroll
  for(int k=0;k<16;k++) acc += xr[k]*bf2f(smW[j*16+k]);
  float xg = gelu_(acc);
  float m = wredsum(xg)*(1.f/64.f);
  float d = xg - m;
  float v = wredsum(d*d)*(1.f/64.f);
  float se = d*rsqrtf(v+1e-5f)*bf2f(lng[j]) + bf2f(lnb[j]);
  fused[b*FUSED_ + 128 + j] = se;
  #pragma unroll
  for(int i=0;i<5;i++){
    float p = se*bf2f(gW[i*64+j]);
    float s = wredsum(p);
    if (j == 0) gates[b*5+i] = sigm(s + bf2f(gb[i]));
  }
}

// ---------------- qkv = (phys*gates)^T @ attn_in_W^T + b ----------------
__global__ __launch_bounds__(448) void qkv_k(const u16* __restrict__ phys,
   const float* __restrict__ gates, const u16* __restrict__ aW,
   const u16* __restrict__ ab, float* __restrict__ qkv)
{
  int b = blockIdx.x, l = threadIdx.x;
  if (l >= PL_) return;
  float pv[5];
  #pragma unroll
  for(int i=0;i<5;i++) pv[i] = bf2f(phys[((size_t)b*5+i)*PL_ + l]) * gates[b*5+i];
  #pragma unroll
  for(int c=0;c<15;c++){
    float a = bf2f(ab[c]);
    #pragma unroll
    for(int i=0;i<5;i++) a += pv[i]*bf2f(aW[c*5+i]);
    qkv[((size_t)b*15+c)*PL_ + l] = a;
  }
}

// ---------------- attention (rank-1 scores, softmax over j) ----------------
__global__ __launch_bounds__(256) void attn_k(const float* __restrict__ qkv,
                                              float* __restrict__ ao)
{
  int h = blockIdx.x, b = blockIdx.y;
  int tid = threadIdx.x;
  __shared__ float kS[PL_], vS[PL_];
  __shared__ float red[32];
  const float* qb = qkv + ((size_t)b*15 + h)*PL_;
  const float* kb = qkv + ((size_t)b*15 + 5 + h)*PL_;
  const float* vb = qkv + ((size_t)b*15 + 10 + h)*PL_;
  for(int j=tid;j<PL_;j+=256){ kS[j]=kb[j]; vS[j]=vb[j]; }
  __syncthreads();
  float lmax=-1e30f, lmin=1e30f;
  for(int j=tid;j<PL_;j+=256){ float kv=kS[j]; lmax=fmaxf(lmax,kv); lmin=fminf(lmin,kv); }
  #pragma unroll
  for(int o=32;o>0;o>>=1){ lmax=fmaxf(lmax,__shfl_xor(lmax,o)); lmin=fminf(lmin,__shfl_xor(lmin,o)); }
  int wv = tid>>6;
  if ((tid&63)==0){ red[wv]=lmax; red[8+wv]=lmin; }
  __syncthreads();
  if (tid==0){
    float mx=red[0], mn=red[8];
    for(int i=1;i<4;i++){ mx=fmaxf(mx,red[i]); mn=fminf(mn,red[8+i]); }
    red[16]=mx; red[17]=mn;
  }
  __syncthreads();
  float kmx=red[16], kmn=red[17];
  for(int i=tid;i<PL_;i+=256){
    float s = qb[i];
    float m = fmaxf(s*kmx, s*kmn);
    float den=0.f, num=0.f;
    #pragma unroll 4
    for(int j=0;j<PL_;j++){
      float e = __expf(s*kS[j]-m);
      den += e; num += e*vS[j];
    }
    ao[((size_t)b*PL_+i)*5 + h] = num/den;
  }
}

// ---------------- output projection ----------------
__global__ __launch_bounds__(448) void proj_k(const float* __restrict__ ao,
   const u16* __restrict__ oW, const u16* __restrict__ ob, float* __restrict__ p2)
{
  int b = blockIdx.x, l = threadIdx.x;
  if (l >= PL_) return;
  float a[5];
  #pragma unroll
  for(int hh=0;hh<5;hh++) a[hh] = ao[((size_t)b*PL_+l)*5 + hh];
  #pragma unroll
  for(int c=0;c<5;c++){
    float s = bf2f(ob[c]);
    #pragma unroll
    for(int hh=0;hh<5;hh++) s += a[hh]*bf2f(oW[c*5+hh]);
    p2[((size_t)b*5+c)*PL_ + l] = s;
  }
}

// ---------------- dilated convs + gelu + mean ----------------
template<int KS, int DIL, int PAD>
__device__ inline void do_conv(const float* pS, const u16* Wc, const u16* bc,
                               float* fused, int b, int o, int p, int cslot)
{
  const int Lout = PL_ + 2*PAD - DIL*(KS-1);
  float w[5][KS];
  #pragma unroll
  for(int i=0;i<5;i++)
    #pragma unroll
    for(int t=0;t<KS;t++) w[i][t] = bf2f(Wc[(o*5+i)*KS + t]);
  float bias = bf2f(bc[o]);
  float acc = 0.f;
  for(int l=p; l<Lout; l+=8){
    float s = bias;
    #pragma unroll
    for(int t=0;t<KS;t++){
      int idx = l - PAD + t*DIL;
      if (idx >= 0 && idx < PL_){
        #pragma unroll
        for(int i=0;i<5;i++) s += w[i][t]*pS[i*PL_ + idx];
      }
    }
    acc += gelu_(s);
  }
  #pragma unroll
  for(int off=1;off<8;off<<=1) acc += __shfl_xor(acc,off);
  if (p == 0) fused[b*FUSED_ + 192 + cslot*32 + o] = acc/(float)Lout;
}

__global__ __launch_bounds__(256) void conv_k(const float* __restrict__ p2,
  const u16* __restrict__ W1c, const u16* __restrict__ b1c,
  const u16* __restrict__ W2c, const u16* __restrict__ b2c,
  const u16* __restrict__ W3c, const u16* __restrict__ b3c,
  float* __restrict__ fused)
{
  int b = blockIdx.x;
  __shared__ float pS[5*PL_];
  for(int idx=threadIdx.x; idx<5*PL_; idx+=256) pS[idx] = p2[(size_t)b*5*PL_ + idx];
  __syncthreads();
  int o = threadIdx.x >> 3, p = threadIdx.x & 7;
  do_conv<3,1,1>(pS, W1c, b1c, fused, b, o, p, 0);
  do_conv<5,2,2>(pS, W2c, b2c, fused, b, o, p, 1);
  do_conv<9,4,4>(pS, W3c, b3c, fused, b, o, p, 2);
}

// ---------------- head: LN + MLP (output dtype adaptive) ----------------
__global__ __launch_bounds__(448) void head_k(const float* __restrict__ fused,
   const u16* __restrict__ lng, const u16* __restrict__ lnb,
   const u16* __restrict__ W1, const u16* __restrict__ b1,
   const u16* __restrict__ W2, const u16* __restrict__ b2,
   void* __restrict__ out, const u16* __restrict__ detect)
{
  const bool isbf = (detect[0] == 0x3F80u);
  int b = blockIdx.x, tid = threadIdx.x;
  __shared__ float fS[FUSED_];
  __shared__ float hS[128];
  __shared__ float red[32];
  float v = (tid < FUSED_) ? fused[b*FUSED_ + tid] : 0.f;
  float s1 = wredsum(v);
  float s2 = wredsum(v*v);
  int wv = tid>>6;
  if ((tid&63)==0){ red[wv]=s1; red[8+wv]=s2; }
  __syncthreads();
  if (tid==0){
    float S=0.f, SS=0.f;
    for(int i=0;i<7;i++){ S+=red[i]; SS+=red[8+i]; }
    float m = S/288.f;
    red[16]=m; red[17]=SS/288.f - m*m;
  }
  __syncthreads();
  float m = red[16], var = red[17];
  if (tid < FUSED_) fS[tid] = (v-m)*rsqrtf(var+1e-5f)*bf2f(lng[tid]) + bf2f(lnb[tid]);
  __syncthreads();
  if (tid < 128){
    float a = bf2f(b1[tid]);
    const u16* wr = W1 + (size_t)tid*FUSED_;
    #pragma unroll
    for(int k8=0;k8<36;k8++){
      uint4 q = *(const uint4*)(wr + k8*8);
      a += fS[8*k8+0]*bf2f((u16)(q.x&0xffffu)) + fS[8*k8+1]*bf2f((u16)(q.x>>16))
         + fS[8*k8+2]*bf2f((u16)(q.y&0xffffu)) + fS[8*k8+3]*bf2f((u16)(q.y>>16))
         + fS[8*k8+4]*bf2f((u16)(q.z&0xffffu)) + fS[8*k8+5]*bf2f((u16)(q.z>>16))
         + fS[8*k8+6]*bf2f((u16)(q.w&0xffffu)) + fS[8*k8+7]*bf2f((u16)(q.w>>16));
    }
    hS[tid] = gelu_(a);
  }
  __syncthreads();
  if (tid < PL_){
    float a = bf2f(b2[tid]);
    const u16* wr = W2 + (size_t)tid*128;
    #pragma unroll
    for(int k8=0;k8<16;k8++){
      uint4 q = *(const uint4*)(wr + k8*8);
      a += hS[8*k8+0]*bf2f((u16)(q.x&0xffffu)) + hS[8*k8+1]*bf2f((u16)(q.x>>16))
         + hS[8*k8+2]*bf2f((u16)(q.y&0xffffu)) + hS[8*k8+3]*bf2f((u16)(q.y>>16))
         + hS[8*k8+4]*bf2f((u16)(q.z&0xffffu)) + hS[8*k8+5]*bf2f((u16)(q.z>>16))
         + hS[8*k8+6]*bf2f((u16)(q.w&0xffffu)) + hS[8*k8+7]*bf2f((u16)(q.w>>16));
    }
    size_t oi = (size_t)b*PL_ + tid;
    if (isbf) ((u16*)out)[oi] = f2bf(a);
    else      ((float*)out)[oi] = a;
  }
}

extern "C" void kernel_launch(void* const* d_in, const int* in_sizes, int n_in,
                              void* d_out, int out_size, void* d_ws, size_t ws_size,
                              hipStream_t stream)
{
  static const unsigned cnts[N_IN] = {
    4194304, 2048, 276480,
    6144, 12288, 192, 192,
    6144, 12288, 192, 192,
    24576, 12288, 192, 192,
    24576, 12288, 192, 192,
    1024, 64, 64, 64,
    320, 5,
    75, 15,
    25, 5,
    480, 32, 800, 32, 1440, 32,
    288, 288,
    36864, 128, 55296, 432
  };

  char* ws = (char*)d_ws;
  size_t off = 0;
  auto alloc = [&](size_t bytes){ size_t o = off; off = (off + bytes + 255) & ~(size_t)255; return o; };

  CvtArgs ca;
  const u16* cin[N_IN];
  unsigned totalBlocks = 0;
  for (int i=0;i<N_IN;i++){
    ca.src[i] = d_in[i];
    ca.cnt[i] = cnts[i];
    size_t o = alloc((size_t)cnts[i]*2);
    ca.dstOff[i] = (unsigned)(o/2);
    cin[i] = (const u16*)(ws + o);
    ca.blkStart[i] = totalBlocks;
    totalBlocks += (cnts[i] + 2047u)/2048u;
  }
  ca.blkStart[N_IN] = totalBlocks;
  u16* canon = (u16*)ws;

  u16*   gi    = (u16*)  (ws + alloc((size_t)2*BT_*G_*2));
  u16*   x1    = (u16*)  (ws + alloc((size_t)BT_*128*2));
  float* fused = (float*)(ws + alloc((size_t)B_*FUSED_*4));
  float* gates = (float*)(ws + alloc((size_t)B_*5*4));
  float* qkv   = (float*)(ws + alloc((size_t)B_*15*PL_*4));
  float* ao    = (float*)(ws + alloc((size_t)B_*PL_*5*4));
  float* p2    = (float*)(ws + alloc((size_t)B_*5*PL_*4));
  (void)ws_size; (void)in_sizes; (void)n_in; (void)out_size;

  convert_k<<<totalBlocks, 256, 0, stream>>>(ca, canon);

  gi_gemm<32><<<BT_/64, 256, 0, stream>>>(cin[0], cin[3], cin[7], cin[5], cin[9], gi);
  recur<<<256, 64, 0, stream>>>(gi, cin[4], cin[8], cin[6], cin[10], x1, nullptr, 0);
  gi_gemm<128><<<BT_/64, 256, 0, stream>>>(x1, cin[11], cin[15], cin[13], cin[17], gi);
  recur<<<256, 64, 0, stream>>>(gi, cin[12], cin[16], cin[14], cin[18], nullptr, fused, 1);
  static_k<<<128, 64, 0, stream>>>(cin[1], cin[19], cin[20], cin[21], cin[22], cin[23], cin[24], fused, gates);
  qkv_k<<<128, 448, 0, stream>>>(cin[2], gates, cin[25], cin[26], qkv);
  attn_k<<<dim3(5,128), 256, 0, stream>>>(qkv, ao);
  proj_k<<<128, 448, 0, stream>>>(ao, cin[27], cin[28], p2);
  conv_k<<<128, 256, 0, stream>>>(p2, cin[29], cin[30], cin[31], cin[32], cin[33], cin[34], fused);
  head_k<<<128, 448, 0, stream>>>(fused, cin[35], cin[36], cin[37], cin[38], cin[39], cin[40],
                                  d_out, (const u16*)d_in[21]);
}

// Round 13
// 1253.540 us; speedup vs baseline: 1.5914x; 1.1531x over previous
//
#include <hip/hip_runtime.h>
#include <stdint.h>

#define B_ 128
#define T_ 1024
#define BT_ (B_*T_)
#define H_ 64
#define G_ 192
#define PL_ 432
#define NP_ 5
#define FUSED_ 288
#define N_IN 41

typedef unsigned short u16;
typedef __attribute__((ext_vector_type(8))) short bf16x8;
typedef __attribute__((ext_vector_type(4))) float f32x4;
typedef _Float16 h2 __attribute__((ext_vector_type(2)));
typedef _Float16 h8 __attribute__((ext_vector_type(8)));

__device__ inline float bf2f(u16 u){ union{float f; unsigned int i;} c; c.i = ((unsigned int)u)<<16; return c.f; }
__device__ inline u16 f2bf(float f){ unsigned int u = __float_as_uint(f); unsigned int r = (u + 0x7fffu + ((u>>16)&1u))>>16; return (u16)r; }
__device__ inline _Float16 bf2h(u16 u){ return (_Float16)bf2f(u); }
__device__ inline float sigm(float x){ return 1.f/(1.f+__expf(-x)); }
__device__ inline float tanh_(float x){ float t = __expf(fminf(fmaxf(2.f*x,-30.f),30.f)); return (t-1.f)/(t+1.f); }
__device__ inline float gelu_(float x){ return 0.5f*x*(1.f + erff(x*0.70710678118654752f)); }
__device__ inline float wredsum(float v){
  #pragma unroll
  for(int o=32;o>0;o>>=1) v += __shfl_xor(v,o);
  return v;
}

#if __has_builtin(__builtin_amdgcn_fdot2)
__device__ inline float dot2(h2 a, h2 b, float c){ return __builtin_amdgcn_fdot2(a, b, c, false); }
#else
__device__ inline float dot2(h2 a, h2 b, float c){ return c + (float)a.x*(float)b.x + (float)a.y*(float)b.y; }
#endif

// ---------------- input canonicalization: anything -> bf16 in ws ----------------
struct CvtArgs {
  const void* src[N_IN];
  unsigned dstOff[N_IN];
  unsigned cnt[N_IN];
  unsigned blkStart[N_IN+1];
};

__global__ __launch_bounds__(256) void convert_k(CvtArgs a, u16* __restrict__ dst){
  const bool isbf = (((const u16*)a.src[21])[0] == 0x3F80u);
  int b = blockIdx.x;
  int lo = 0, hi = N_IN;
  while (hi - lo > 1){ int mid = (lo+hi)>>1; if (a.blkStart[mid] <= (unsigned)b) lo = mid; else hi = mid; }
  const int i = lo;
  const unsigned lb = (unsigned)b - a.blkStart[i];
  const unsigned n = a.cnt[i];
  u16* d = dst + a.dstOff[i];
  if (isbf){
    const u16* s = (const u16*)a.src[i];
    #pragma unroll
    for(int e=0;e<8;e++){ unsigned idx = lb*2048u + e*256u + threadIdx.x; if (idx < n) d[idx] = s[idx]; }
  } else {
    const float* s = (const float*)a.src[i];
    #pragma unroll
    for(int e=0;e<8;e++){ unsigned idx = lb*2048u + e*256u + threadIdx.x; if (idx < n) d[idx] = f2bf(s[idx]); }
  }
}

// ---------------- gi = A @ [Wf;Wb]^T + [bf;bb]  (bf16 MFMA GEMM) ----------------
template<int K>
__global__ __launch_bounds__(256) void gi_gemm(const u16* __restrict__ A,
    const u16* __restrict__ Wf, const u16* __restrict__ Wb,
    const u16* __restrict__ biasF, const u16* __restrict__ biasB,
    u16* __restrict__ out)
{
  const int wv = threadIdx.x >> 6, lane = threadIdx.x & 63;
  const int l15 = lane & 15, quad = lane >> 4;
  const size_t mBase = (size_t)blockIdx.x*64 + wv*16;

  bf16x8 afr[K/32];
  #pragma unroll
  for(int kc=0;kc<K/32;kc++)
    afr[kc] = *(const bf16x8*)(A + (mBase + l15)*K + kc*32 + quad*8);

  #pragma unroll
  for(int half=0; half<2; ++half){
    const u16* W    = half ? Wb : Wf;
    const u16* bias = half ? biasB : biasF;
    u16* o = out + (size_t)half * BT_ * G_;
    for(int nt=0; nt<12; ++nt){
      int n = nt*16 + l15;
      f32x4 acc = {0.f,0.f,0.f,0.f};
      #pragma unroll
      for(int kc=0;kc<K/32;kc++){
        bf16x8 bfr = *(const bf16x8*)(W + n*K + kc*32 + quad*8);
        acc = __builtin_amdgcn_mfma_f32_16x16x32_bf16(afr[kc], bfr, acc, 0,0,0);
      }
      float bv = bf2f(bias[n]);
      #pragma unroll
      for(int r=0;r<4;r++){
        size_t row = mBase + quad*4 + r;
        o[row*G_ + n] = f2bf(acc[r] + bv);
      }
    }
  }
}

// ---------------- GRU recurrence: ONE WAVE per (dir, b) chain ----------------
// R9-exact (best measured: 476us/dispatch). 256 blocks x 64 threads = 1
// wave/CU. Lane j owns rows j (r), 64+j (z), 128+j (n) of Whh as packed f16
// pairs (96 VGPRs, VGPR_Count=132, no spill thanks to waves_per_eu(1,1)).
// gi staged global->LDS in 16-step chunks via async global_load_lds
// (6 x 1KB DMA, double-buffered, ONE vmcnt(0) per 16 steps). Matvec = 96
// v_dot2_f32_f16. No barriers: single-wave lockstep + in-order DS.
// R10/R11/R12 post-mortems: the ~1161cyc/step is exposed serial latency
// (LDS h RAW + in-order DS + transcendental chain), not issue -- structural
// rewrites (multi-wave, MFMA) all regressed from this point.
__global__ __launch_bounds__(64)
__attribute__((amdgpu_waves_per_eu(1,1)))
void recur(const u16* __restrict__ gi,
    const u16* __restrict__ WhF, const u16* __restrict__ WhB,
    const u16* __restrict__ bhF, const u16* __restrict__ bhB,
    u16* __restrict__ y_x1, float* __restrict__ hfin, int layer)
{
  const int chain = blockIdx.x;
  const int dir = chain >> 7;
  const int b = chain & 127;
  const int j = threadIdx.x;           // lane 0..63
  const u16* Wh = dir ? WhB : WhF;
  const u16* bh = dir ? bhB : bhF;

  // this lane's three Whh rows as packed f16 pairs (bf16->f16 is exact)
  h2 wr[32], wz[32], wn[32];
  #pragma unroll
  for(int k8=0;k8<8;k8++){
    uint4 q;
    q = *(const uint4*)(Wh + (size_t)j*64 + k8*8);
    wr[4*k8+0] = (h2){bf2h((u16)(q.x&0xffffu)), bf2h((u16)(q.x>>16))};
    wr[4*k8+1] = (h2){bf2h((u16)(q.y&0xffffu)), bf2h((u16)(q.y>>16))};
    wr[4*k8+2] = (h2){bf2h((u16)(q.z&0xffffu)), bf2h((u16)(q.z>>16))};
    wr[4*k8+3] = (h2){bf2h((u16)(q.w&0xffffu)), bf2h((u16)(q.w>>16))};
    q = *(const uint4*)(Wh + (size_t)(64+j)*64 + k8*8);
    wz[4*k8+0] = (h2){bf2h((u16)(q.x&0xffffu)), bf2h((u16)(q.x>>16))};
    wz[4*k8+1] = (h2){bf2h((u16)(q.y&0xffffu)), bf2h((u16)(q.y>>16))};
    wz[4*k8+2] = (h2){bf2h((u16)(q.z&0xffffu)), bf2h((u16)(q.z>>16))};
    wz[4*k8+3] = (h2){bf2h((u16)(q.w&0xffffu)), bf2h((u16)(q.w>>16))};
    q = *(const uint4*)(Wh + (size_t)(128+j)*64 + k8*8);
    wn[4*k8+0] = (h2){bf2h((u16)(q.x&0xffffu)), bf2h((u16)(q.x>>16))};
    wn[4*k8+1] = (h2){bf2h((u16)(q.y&0xffffu)), bf2h((u16)(q.y>>16))};
    wn[4*k8+2] = (h2){bf2h((u16)(q.z&0xffffu)), bf2h((u16)(q.z>>16))};
    wn[4*k8+3] = (h2){bf2h((u16)(q.w&0xffffu)), bf2h((u16)(q.w>>16))};
  }
  const float bhr = bf2f(bh[j]), bhz = bf2f(bh[64+j]), bhn = bf2f(bh[128+j]);

  __shared__ __align__(16) u16 giLds[2][3072];   // 2 x 16 steps x 192 u16
  __shared__ _Float16 hSf[64];
  h8* hS8 = (h8*)hSf;
  hSf[j] = (_Float16)0.f;              // in-order DS: visible to the loop's reads

  const u16* giC = gi + (size_t)chain * T_ * G_;

  // async chunk DMA: 16 rows (6144 B) as 6 x (64 lanes x 16 B)
  auto issue_chunk = [&](int c, int buf){
    int tbase = dir ? (1008 - c*16) : (c*16);
    const u16* src = giC + (size_t)tbase*G_ + j*8;
    u16* dst = &giLds[buf][0];
    #pragma unroll
    for(int i=0;i<6;i++){
      __builtin_amdgcn_global_load_lds(
        (const __attribute__((address_space(1))) void*)(src + i*512),
        (__attribute__((address_space(3))) void*)(dst + i*512), 16, 0, 0);
    }
  };

  issue_chunk(0, 0);

  float h = 0.f;
  for(int c=0; c<64; ++c){
    asm volatile("s_waitcnt vmcnt(0)" ::: "memory");  // chunk c landed in LDS
    if (c < 63) issue_chunk(c+1, (c+1)&1);
    const u16* gbuf = &giLds[c&1][0];
    #pragma unroll 2
    for(int ls=0; ls<16; ++ls){
      int row = dir ? (15-ls) : ls;
      const u16* rowp = gbuf + row*G_;
      // matvec: 96 dot2 ops, 2 f32 accumulators per gate
      float r0=bhr, r1=0.f, z0=bhz, z1=0.f, n0=bhn, n1=0.f;
      #pragma unroll
      for(int k=0;k<8;k++){
        h8 hv = hS8[k];
        h2 p0 = __builtin_shufflevector(hv, hv, 0, 1);
        h2 p1 = __builtin_shufflevector(hv, hv, 2, 3);
        h2 p2 = __builtin_shufflevector(hv, hv, 4, 5);
        h2 p3 = __builtin_shufflevector(hv, hv, 6, 7);
        r0 = dot2(wr[4*k+0], p0, r0); r1 = dot2(wr[4*k+1], p1, r1);
        r0 = dot2(wr[4*k+2], p2, r0); r1 = dot2(wr[4*k+3], p3, r1);
        z0 = dot2(wz[4*k+0], p0, z0); z1 = dot2(wz[4*k+1], p1, z1);
        z0 = dot2(wz[4*k+2], p2, z0); z1 = dot2(wz[4*k+3], p3, z1);
        n0 = dot2(wn[4*k+0], p0, n0); n1 = dot2(wn[4*k+1], p1, n1);
        n0 = dot2(wn[4*k+2], p2, n0); n1 = dot2(wn[4*k+3], p3, n1);
      }
      float gr = bf2f(rowp[j]), gz = bf2f(rowp[64+j]), gn = bf2f(rowp[128+j]);

      float r  = sigm(gr + (r0+r1));
      float z  = sigm(gz + (z0+z1));
      float nn = tanh_(gn + r*(n0+n1));
      h = (1.f - z)*nn + z*h;

      hSf[j] = (_Float16)h;            // in-order DS; next iter's reads see it

      if (layer == 0){
        int s = c*16 + ls;
        int t = dir ? (T_-1-s) : s;
        y_x1[((size_t)b*T_ + t)*128 + dir*64 + j] = f2bf(h);
      }
    }
  }
  if (layer == 1) hfin[b*FUSED_ + dir*64 + j] = h;
}

// ---------------- fused static branch + qkv (gates stay in LDS) ----------------
__global__ __launch_bounds__(448) void staticqkv_k(const u16* __restrict__ sx,
   const u16* __restrict__ smW, const u16* __restrict__ smb,
   const u16* __restrict__ lng, const u16* __restrict__ lnb,
   const u16* __restrict__ gW, const u16* __restrict__ gb,
   const u16* __restrict__ phys, const u16* __restrict__ aW,
   const u16* __restrict__ ab,
   float* __restrict__ fused, float* __restrict__ qkv)
{
  int b = blockIdx.x, tid = threadIdx.x;
  __shared__ float gS[5];
  if (tid < 64){
    int j = tid;
    float xr[16];
    #pragma unroll
    for(int k=0;k<16;k++) xr[k] = bf2f(sx[b*16+k]);
    float acc = bf2f(smb[j]);
    #pragma unroll
    for(int k=0;k<16;k++) acc += xr[k]*bf2f(smW[j*16+k]);
    float xg = gelu_(acc);
    float m = wredsum(xg)*(1.f/64.f);
    float d = xg - m;
    float v = wredsum(d*d)*(1.f/64.f);
    float se = d*rsqrtf(v+1e-5f)*bf2f(lng[j]) + bf2f(lnb[j]);
    fused[b*FUSED_ + 128 + j] = se;
    #pragma unroll
    for(int i=0;i<5;i++){
      float p = se*bf2f(gW[i*64+j]);
      float s = wredsum(p);
      if (j == 0) gS[i] = sigm(s + bf2f(gb[i]));
    }
  }
  __syncthreads();
  int l = tid;
  if (l < PL_){
    float pv[5];
    #pragma unroll
    for(int i=0;i<5;i++) pv[i] = bf2f(phys[((size_t)b*5+i)*PL_ + l]) * gS[i];
    #pragma unroll
    for(int c=0;c<15;c++){
      float a = bf2f(ab[c]);
      #pragma unroll
      for(int i=0;i<5;i++) a += pv[i]*bf2f(aW[c*5+i]);
      qkv[((size_t)b*15+c)*PL_ + l] = a;
    }
  }
}

// ---------------- attention (rank-1 scores, softmax over j) ----------------
__global__ __launch_bounds__(256) void attn_k(const float* __restrict__ qkv,
                                              float* __restrict__ ao)
{
  int h = blockIdx.x, b = blockIdx.y;
  int tid = threadIdx.x;
  __shared__ float kS[PL_], vS[PL_];
  __shared__ float red[32];
  const float* qb = qkv + ((size_t)b*15 + h)*PL_;
  const float* kb = qkv + ((size_t)b*15 + 5 + h)*PL_;
  const float* vb = qkv + ((size_t)b*15 + 10 + h)*PL_;
  for(int j=tid;j<PL_;j+=256){ kS[j]=kb[j]; vS[j]=vb[j]; }
  __syncthreads();
  float lmax=-1e30f, lmin=1e30f;
  for(int j=tid;j<PL_;j+=256){ float kv=kS[j]; lmax=fmaxf(lmax,kv); lmin=fminf(lmin,kv); }
  #pragma unroll
  for(int o=32;o>0;o>>=1){ lmax=fmaxf(lmax,__shfl_xor(lmax,o)); lmin=fminf(lmin,__shfl_xor(lmin,o)); }
  int wv = tid>>6;
  if ((tid&63)==0){ red[wv]=lmax; red[8+wv]=lmin; }
  __syncthreads();
  if (tid==0){
    float mx=red[0], mn=red[8];
    for(int i=1;i<4;i++){ mx=fmaxf(mx,red[i]); mn=fminf(mn,red[8+i]); }
    red[16]=mx; red[17]=mn;
  }
  __syncthreads();
  float kmx=red[16], kmn=red[17];
  for(int i=tid;i<PL_;i+=256){
    float s = qb[i];
    float m = fmaxf(s*kmx, s*kmn);
    float den=0.f, num=0.f;
    #pragma unroll 4
    for(int j=0;j<PL_;j++){
      float e = __expf(s*kS[j]-m);
      den += e; num += e*vS[j];
    }
    ao[((size_t)b*PL_+i)*5 + h] = num/den;
  }
}

// ---------------- fused output projection + dilated convs (p2 stays in LDS) ----------------
template<int KS, int DIL, int PAD>
__device__ inline void do_conv(const float* pS, const u16* Wc, const u16* bc,
                               float* fused, int b, int o, int p, int cslot)
{
  const int Lout = PL_ + 2*PAD - DIL*(KS-1);
  float w[5][KS];
  #pragma unroll
  for(int i=0;i<5;i++)
    #pragma unroll
    for(int t=0;t<KS;t++) w[i][t] = bf2f(Wc[(o*5+i)*KS + t]);
  float bias = bf2f(bc[o]);
  float acc = 0.f;
  for(int l=p; l<Lout; l+=8){
    float s = bias;
    #pragma unroll
    for(int t=0;t<KS;t++){
      int idx = l - PAD + t*DIL;
      if (idx >= 0 && idx < PL_){
        #pragma unroll
        for(int i=0;i<5;i++) s += w[i][t]*pS[i*PL_ + idx];
      }
    }
    acc += gelu_(s);
  }
  #pragma unroll
  for(int off=1;off<8;off<<=1) acc += __shfl_xor(acc,off);
  if (p == 0) fused[b*FUSED_ + 192 + cslot*32 + o] = acc/(float)Lout;
}

__global__ __launch_bounds__(256) void projconv_k(const float* __restrict__ ao,
  const u16* __restrict__ oW, const u16* __restrict__ ob,
  const u16* __restrict__ W1c, const u16* __restrict__ b1c,
  const u16* __restrict__ W2c, const u16* __restrict__ b2c,
  const u16* __restrict__ W3c, const u16* __restrict__ b3c,
  float* __restrict__ fused)
{
  int b = blockIdx.x, tid = threadIdx.x;
  __shared__ float pS[5*PL_];
  for(int l=tid; l<PL_; l+=256){
    float a[5];
    #pragma unroll
    for(int hh=0;hh<5;hh++) a[hh] = ao[((size_t)b*PL_+l)*5 + hh];
    #pragma unroll
    for(int c=0;c<5;c++){
      float s = bf2f(ob[c]);
      #pragma unroll
      for(int hh=0;hh<5;hh++) s += a[hh]*bf2f(oW[c*5+hh]);
      pS[c*PL_ + l] = s;
    }
  }
  __syncthreads();
  int o = tid >> 3, p = tid & 7;
  do_conv<3,1,1>(pS, W1c, b1c, fused, b, o, p, 0);
  do_conv<5,2,2>(pS, W2c, b2c, fused, b, o, p, 1);
  do_conv<9,4,4>(pS, W3c, b3c, fused, b, o, p, 2);
}

// ---------------- head: LN + MLP (output dtype adaptive) ----------------
__global__ __launch_bounds__(448) void head_k(const float* __restrict__ fused,
   const u16* __restrict__ lng, const u16* __restrict__ lnb,
   const u16* __restrict__ W1, const u16* __restrict__ b1,
   const u16* __restrict__ W2, const u16* __restrict__ b2,
   void* __restrict__ out, const u16* __restrict__ detect)
{
  const bool isbf = (detect[0] == 0x3F80u);
  int b = blockIdx.x, tid = threadIdx.x;
  __shared__ float fS[FUSED_];
  __shared__ float hS[128];
  __shared__ float red[32];
  float v = (tid < FUSED_) ? fused[b*FUSED_ + tid] : 0.f;
  float s1 = wredsum(v);
  float s2 = wredsum(v*v);
  int wv = tid>>6;
  if ((tid&63)==0){ red[wv]=s1; red[8+wv]=s2; }
  __syncthreads();
  if (tid==0){
    float S=0.f, SS=0.f;
    for(int i=0;i<7;i++){ S+=red[i]; SS+=red[8+i]; }
    float m = S/288.f;
    red[16]=m; red[17]=SS/288.f - m*m;
  }
  __syncthreads();
  float m = red[16], var = red[17];
  if (tid < FUSED_) fS[tid] = (v-m)*rsqrtf(var+1e-5f)*bf2f(lng[tid]) + bf2f(lnb[tid]);
  __syncthreads();
  if (tid < 128){
    float a = bf2f(b1[tid]);
    const u16* wr = W1 + (size_t)tid*FUSED_;
    #pragma unroll
    for(int k8=0;k8<36;k8++){
      uint4 q = *(const uint4*)(wr + k8*8);
      a += fS[8*k8+0]*bf2f((u16)(q.x&0xffffu)) + fS[8*k8+1]*bf2f((u16)(q.x>>16))
         + fS[8*k8+2]*bf2f((u16)(q.y&0xffffu)) + fS[8*k8+3]*bf2f((u16)(q.y>>16))
         + fS[8*k8+4]*bf2f((u16)(q.z&0xffffu)) + fS[8*k8+5]*bf2f((u16)(q.z>>16))
         + fS[8*k8+6]*bf2f((u16)(q.w&0xffffu)) + fS[8*k8+7]*bf2f((u16)(q.w>>16));
    }
    hS[tid] = gelu_(a);
  }
  __syncthreads();
  if (tid < PL_){
    float a = bf2f(b2[tid]);
    const u16* wr = W2 + (size_t)tid*128;
    #pragma unroll
    for(int k8=0;k8<16;k8++){
      uint4 q = *(const uint4*)(wr + k8*8);
      a += hS[8*k8+0]*bf2f((u16)(q.x&0xffffu)) + hS[8*k8+1]*bf2f((u16)(q.x>>16))
         + hS[8*k8+2]*bf2f((u16)(q.y&0xffffu)) + hS[8*k8+3]*bf2f((u16)(q.y>>16))
         + hS[8*k8+4]*bf2f((u16)(q.z&0xffffu)) + hS[8*k8+5]*bf2f((u16)(q.z>>16))
         + hS[8*k8+6]*bf2f((u16)(q.w&0xffffu)) + hS[8*k8+7]*bf2f((u16)(q.w>>16));
    }
    size_t oi = (size_t)b*PL_ + tid;
    if (isbf) ((u16*)out)[oi] = f2bf(a);
    else      ((float*)out)[oi] = a;
  }
}

extern "C" void kernel_launch(void* const* d_in, const int* in_sizes, int n_in,
                              void* d_out, int out_size, void* d_ws, size_t ws_size,
                              hipStream_t stream)
{
  static const unsigned cnts[N_IN] = {
    4194304, 2048, 276480,
    6144, 12288, 192, 192,
    6144, 12288, 192, 192,
    24576, 12288, 192, 192,
    24576, 12288, 192, 192,
    1024, 64, 64, 64,
    320, 5,
    75, 15,
    25, 5,
    480, 32, 800, 32, 1440, 32,
    288, 288,
    36864, 128, 55296, 432
  };

  char* ws = (char*)d_ws;
  size_t off = 0;
  auto alloc = [&](size_t bytes){ size_t o = off; off = (off + bytes + 255) & ~(size_t)255; return o; };

  CvtArgs ca;
  const u16* cin[N_IN];
  unsigned totalBlocks = 0;
  for (int i=0;i<N_IN;i++){
    ca.src[i] = d_in[i];
    ca.cnt[i] = cnts[i];
    size_t o = alloc((size_t)cnts[i]*2);
    ca.dstOff[i] = (unsigned)(o/2);
    cin[i] = (const u16*)(ws + o);
    ca.blkStart[i] = totalBlocks;
    totalBlocks += (cnts[i] + 2047u)/2048u;
  }
  ca.blkStart[N_IN] = totalBlocks;
  u16* canon = (u16*)ws;

  u16*   gi    = (u16*)  (ws + alloc((size_t)2*BT_*G_*2));
  u16*   x1    = (u16*)  (ws + alloc((size_t)BT_*128*2));
  float* fused = (float*)(ws + alloc((size_t)B_*FUSED_*4));
  float* qkv   = (float*)(ws + alloc((size_t)B_*15*PL_*4));
  float* ao    = (float*)(ws + alloc((size_t)B_*PL_*5*4));
  (void)ws_size; (void)in_sizes; (void)n_in; (void)out_size;

  convert_k<<<totalBlocks, 256, 0, stream>>>(ca, canon);

  gi_gemm<32><<<BT_/64, 256, 0, stream>>>(cin[0], cin[3], cin[7], cin[5], cin[9], gi);
  recur<<<256, 64, 0, stream>>>(gi, cin[4], cin[8], cin[6], cin[10], x1, nullptr, 0);
  gi_gemm<128><<<BT_/64, 256, 0, stream>>>(x1, cin[11], cin[15], cin[13], cin[17], gi);
  recur<<<256, 64, 0, stream>>>(gi, cin[12], cin[16], cin[14], cin[18], nullptr, fused, 1);
  staticqkv_k<<<128, 448, 0, stream>>>(cin[1], cin[19], cin[20], cin[21], cin[22],
                                       cin[23], cin[24], cin[2], cin[25], cin[26],
                                       fused, qkv);
  attn_k<<<dim3(5,128), 256, 0, stream>>>(qkv, ao);
  projconv_k<<<128, 256, 0, stream>>>(ao, cin[27], cin[28], cin[29], cin[30],
                                      cin[31], cin[32], cin[33], cin[34], fused);
  head_k<<<128, 448, 0, stream>>>(fused, cin[35], cin[36], cin[37], cin[38], cin[39], cin[40],
                                  d_out, (const u16*)d_in[21]);
}